// Round 1
// baseline (318.807 us; speedup 1.0000x reference)
//
#include <hip/hip_runtime.h>
#include <stdint.h>

#define Bz 2
#define Tq 1024
#define Mm 1024
#define Hh 16
#define Ll 2048
#define Rr 3072

typedef __attribute__((ext_vector_type(8))) short bf16x8;
typedef __attribute__((ext_vector_type(4))) float f32x4;

typedef __attribute__((address_space(3))) uint8_t lds_u8_t;
typedef __attribute__((address_space(1))) uint8_t glb_u8_t;

__device__ __forceinline__ void gl2lds16(const void* g, void* l) {
  __builtin_amdgcn_global_load_lds((const glb_u8_t*)g, (lds_u8_t*)l, 16, 0, 0);
}

__device__ __forceinline__ unsigned short f2bf(float f) {
  unsigned int u = __builtin_bit_cast(unsigned int, f);
  u = u + 0x7fffu + ((u >> 16) & 1u);
  return (unsigned short)(u >> 16);
}

// ---------------- prep: concat(memory, inputs) -> bf16 values [B*L,1024] ----
__global__ __launch_bounds__(256) void k_vin(const float* __restrict__ x,
                                             const float* __restrict__ mem,
                                             unsigned short* __restrict__ vin) {
  int idx = blockIdx.x * 256 + threadIdx.x;
  int e = idx << 2;
  int row = e >> 10, col = e & 1023;
  int b = row >> 11, l = row & 2047;
  const float* s = (l < Mm) ? (mem + (((size_t)b * Mm + l) << 10) + col)
                            : (x + (((size_t)b * Tq + (l - Mm)) << 10) + col);
  float4 v = *(const float4*)s;
  ushort4 o;
  o.x = f2bf(v.x); o.y = f2bf(v.y); o.z = f2bf(v.z); o.w = f2bf(v.w);
  *(ushort4*)(vin + e) = o;
}

// ---------------- prep: positional encodings fp32->bf16 ---------------------
__global__ __launch_bounds__(256) void k_castp(const float* __restrict__ p,
                                               unsigned short* __restrict__ o) {
  int idx = blockIdx.x * 256 + threadIdx.x;
  int e = idx << 2;
  float4 v = *(const float4*)(p + e);
  ushort4 t;
  t.x = f2bf(v.x); t.y = f2bf(v.y); t.z = f2bf(v.z); t.w = f2bf(v.w);
  *(ushort4*)(o + e) = t;
}

// ---------------- prep: transpose-cast 5 weight matrices (1024x1024) --------
__global__ __launch_bounds__(256) void k_wtall(
    const float* __restrict__ w0, const float* __restrict__ w1,
    const float* __restrict__ w2, const float* __restrict__ w3,
    const float* __restrict__ w4,
    unsigned short* __restrict__ t0, unsigned short* __restrict__ t1,
    unsigned short* __restrict__ t2, unsigned short* __restrict__ t3,
    unsigned short* __restrict__ t4) {
  const float* W;
  unsigned short* WT;
  switch (blockIdx.z) {
    case 0: W = w0; WT = t0; break;
    case 1: W = w1; WT = t1; break;
    case 2: W = w2; WT = t2; break;
    case 3: W = w3; WT = t3; break;
    default: W = w4; WT = t4; break;
  }
  __shared__ float tile[64][65];
  int k0 = blockIdx.x * 64, n0 = blockIdx.y * 64;
  int tid = threadIdx.x;
  int rr = tid >> 4, c4 = (tid & 15) * 4;
#pragma unroll
  for (int it = 0; it < 4; ++it) {
    int r = rr + it * 16;
    float4 v = *(const float4*)(W + (size_t)(k0 + r) * 1024 + n0 + c4);
    tile[r][c4] = v.x; tile[r][c4 + 1] = v.y;
    tile[r][c4 + 2] = v.z; tile[r][c4 + 3] = v.w;
  }
  __syncthreads();
#pragma unroll
  for (int it = 0; it < 4; ++it) {
    int n = rr + it * 16;
    ushort4 o;
    o.x = f2bf(tile[c4 + 0][n]); o.y = f2bf(tile[c4 + 1][n]);
    o.z = f2bf(tile[c4 + 2][n]); o.w = f2bf(tile[c4 + 3][n]);
    *(ushort4*)(WT + (size_t)(n0 + n) * 1024 + k0 + c4) = o;
  }
}

// ---------------- bf16 NT GEMM core (m97 structure, K=1024) -----------------
// C[m][n] = sum_k A[m][k] * Bt[n][k]; 128x128 tile, BK=32, 4 waves 2x2.
// LDS [128 rows][4 chunks of 16B], chunk XOR-swizzled by ((r>>1)&3) on the
// GLOBAL side (global_load_lds dest is base + lane*16, cannot pad).
template <int RMAP>
__device__ __forceinline__ void gemm_core(const unsigned short* __restrict__ A,
                                          const unsigned short* __restrict__ Bt,
                                          int m0, int n0, unsigned short* As,
                                          unsigned short* Bs, f32x4 acc[4][4]) {
  const int tid = threadIdx.x;
  const int w = tid >> 6, lane = tid & 63;
  const int quad = lane >> 4, li = lane & 15;
  const int wr = w >> 1, wc = w & 1;
  f32x4 z = {0.f, 0.f, 0.f, 0.f};
#pragma unroll
  for (int mi = 0; mi < 4; ++mi)
#pragma unroll
    for (int ni = 0; ni < 4; ++ni) acc[mi][ni] = z;

  const int rs = lane >> 2;  // row within 16-row chunk
  const int cs = lane & 3;   // lds 16B slot

  for (int k0 = 0; k0 < 1024; k0 += 32) {
    __syncthreads();
#pragma unroll
    for (int s = 0; s < 2; ++s) {
      int i = w * 2 + s;
      int r = i * 16 + rs;
      int c = cs ^ ((r >> 1) & 3);
      int ar = m0 + r;
      if (RMAP) ar = ar + 1024 + (ar & 1024);  // q rows -> values rows
      gl2lds16(A + (size_t)ar * 1024 + k0 + c * 8, (char*)As + i * 1024);
      int br = n0 + r;
      gl2lds16(Bt + (size_t)br * 1024 + k0 + c * 8, (char*)Bs + i * 1024);
    }
    __syncthreads();
    bf16x8 af[4], bfr[4];
#pragma unroll
    for (int mi = 0; mi < 4; ++mi) {
      int r = wr * 64 + mi * 16 + li;
      int ch = quad ^ ((r >> 1) & 3);
      af[mi] = *(const bf16x8*)((const char*)As + r * 64 + ch * 16);
    }
#pragma unroll
    for (int ni = 0; ni < 4; ++ni) {
      int r = wc * 64 + ni * 16 + li;
      int ch = quad ^ ((r >> 1) & 3);
      bfr[ni] = *(const bf16x8*)((const char*)Bs + r * 64 + ch * 16);
    }
#pragma unroll
    for (int mi = 0; mi < 4; ++mi)
#pragma unroll
      for (int ni = 0; ni < 4; ++ni)
        acc[mi][ni] = __builtin_amdgcn_mfma_f32_16x16x32_bf16(
            af[mi], bfr[ni], acc[mi][ni], 0, 0, 0);
  }
}

// q-projection: dual output qw = q + r_w_bias, qr = q + r_r_bias (bf16)
__global__ __launch_bounds__(256) void k_gemm_q(
    const unsigned short* __restrict__ Vin, const unsigned short* __restrict__ WqT,
    const float* __restrict__ rwb, const float* __restrict__ rrb,
    unsigned short* __restrict__ qwo, unsigned short* __restrict__ qro) {
  __shared__ unsigned short As[128 * 32];
  __shared__ unsigned short Bs[128 * 32];
  int m0 = blockIdx.x * 128, n0 = blockIdx.y * 128;
  f32x4 acc[4][4];
  gemm_core<1>(Vin, WqT, m0, n0, As, Bs, acc);
  const int tid = threadIdx.x, w = tid >> 6, lane = tid & 63;
  const int quad = lane >> 4, li = lane & 15, wr = w >> 1, wc = w & 1;
#pragma unroll
  for (int mi = 0; mi < 4; ++mi)
#pragma unroll
    for (int ni = 0; ni < 4; ++ni) {
      int cc = n0 + wc * 64 + ni * 16 + li;
      float bw_ = rwb[cc], br_ = rrb[cc];
#pragma unroll
      for (int reg = 0; reg < 4; ++reg) {
        int rrow = m0 + wr * 64 + mi * 16 + quad * 4 + reg;
        size_t off = (size_t)rrow * 1024 + cc;
        qwo[off] = f2bf(acc[mi][ni][reg] + bw_);
        qro[off] = f2bf(acc[mi][ni][reg] + br_);
      }
    }
}

// fused k|v projection (shared A staging pattern, N split by blockIdx.y)
__global__ __launch_bounds__(256) void k_gemm_kv(
    const unsigned short* __restrict__ Vin, const unsigned short* __restrict__ WkT,
    const unsigned short* __restrict__ WvT, unsigned short* __restrict__ kb,
    unsigned short* __restrict__ vb) {
  __shared__ unsigned short As[128 * 32];
  __shared__ unsigned short Bs[128 * 32];
  int m0 = blockIdx.x * 128;
  const unsigned short* Bt;
  unsigned short* C;
  int n0;
  if (blockIdx.y < 8) { Bt = WkT; C = kb; n0 = blockIdx.y * 128; }
  else                { Bt = WvT; C = vb; n0 = (blockIdx.y - 8) * 128; }
  f32x4 acc[4][4];
  gemm_core<0>(Vin, Bt, m0, n0, As, Bs, acc);
  const int tid = threadIdx.x, w = tid >> 6, lane = tid & 63;
  const int quad = lane >> 4, li = lane & 15, wr = w >> 1, wc = w & 1;
#pragma unroll
  for (int mi = 0; mi < 4; ++mi)
#pragma unroll
    for (int ni = 0; ni < 4; ++ni)
#pragma unroll
      for (int reg = 0; reg < 4; ++reg) {
        int rrow = m0 + wr * 64 + mi * 16 + quad * 4 + reg;
        int cc = n0 + wc * 64 + ni * 16 + li;
        C[(size_t)rrow * 1024 + cc] = f2bf(acc[mi][ni][reg]);
      }
}

// rk projection (plain bf16 out)
__global__ __launch_bounds__(256) void k_gemm_rk(
    const unsigned short* __restrict__ Pb, const unsigned short* __restrict__ WrT,
    unsigned short* __restrict__ rkb) {
  __shared__ unsigned short As[128 * 32];
  __shared__ unsigned short Bs[128 * 32];
  int m0 = blockIdx.x * 128, n0 = blockIdx.y * 128;
  f32x4 acc[4][4];
  gemm_core<0>(Pb, WrT, m0, n0, As, Bs, acc);
  const int tid = threadIdx.x, w = tid >> 6, lane = tid & 63;
  const int quad = lane >> 4, li = lane & 15, wr = w >> 1, wc = w & 1;
#pragma unroll
  for (int mi = 0; mi < 4; ++mi)
#pragma unroll
    for (int ni = 0; ni < 4; ++ni)
#pragma unroll
      for (int reg = 0; reg < 4; ++reg) {
        int rrow = m0 + wr * 64 + mi * 16 + quad * 4 + reg;
        int cc = n0 + wc * 64 + ni * 16 + li;
        rkb[(size_t)rrow * 1024 + cc] = f2bf(acc[mi][ni][reg]);
      }
}

// output projection (fp32 out -> d_out)
__global__ __launch_bounds__(256) void k_gemm_out(
    const unsigned short* __restrict__ attnb, const unsigned short* __restrict__ WoT,
    float* __restrict__ out) {
  __shared__ unsigned short As[128 * 32];
  __shared__ unsigned short Bs[128 * 32];
  int m0 = blockIdx.x * 128, n0 = blockIdx.y * 128;
  f32x4 acc[4][4];
  gemm_core<0>(attnb, WoT, m0, n0, As, Bs, acc);
  const int tid = threadIdx.x, w = tid >> 6, lane = tid & 63;
  const int quad = lane >> 4, li = lane & 15, wr = w >> 1, wc = w & 1;
#pragma unroll
  for (int mi = 0; mi < 4; ++mi)
#pragma unroll
    for (int ni = 0; ni < 4; ++ni)
#pragma unroll
      for (int reg = 0; reg < 4; ++reg) {
        int rrow = m0 + wr * 64 + mi * 16 + quad * 4 + reg;
        int cc = n0 + wc * 64 + ni * 16 + li;
        out[(size_t)rrow * 1024 + cc] = acc[mi][ni][reg];
      }
}

// ---------------- v transpose: vb[b,l,h,dv] -> vt[b,h,dv,l] -----------------
__global__ __launch_bounds__(256) void k_vt(const unsigned short* __restrict__ vb,
                                            unsigned short* __restrict__ vt) {
  int id = blockIdx.x * 256 + threadIdx.x;  // 524288 total
  int bh = id >> 14;
  int rem = id & 16383;
  int lc = rem >> 6, dv = rem & 63;
  int b = bh >> 4, h = bh & 15;
  int l0 = lc * 8;
  unsigned short tmp[8];
#pragma unroll
  for (int e = 0; e < 8; ++e)
    tmp[e] = vb[((size_t)((b * Ll + l0 + e) * Hh + h)) * 64 + dv];
  ushort4 o1 = {tmp[0], tmp[1], tmp[2], tmp[3]};
  ushort4 o2 = {tmp[4], tmp[5], tmp[6], tmp[7]};
  unsigned short* dst = vt + ((size_t)(bh * 64 + dv)) * Ll + l0;
  *(ushort4*)(dst) = o1;
  *(ushort4*)(dst + 4) = o2;
}

// ---------------- flash attention with TXL relative shift -------------------
// grid (T/64, H, B); 4 waves, wave w owns q rows [qt*64+w*16, +16).
// rel[t,j] = qr[t] . rk[T - t + j]; per-wave band of 80 rel columns.
__global__ __launch_bounds__(256, 2) void k_attn(
    const unsigned short* __restrict__ qw, const unsigned short* __restrict__ qr,
    const unsigned short* __restrict__ kb, const unsigned short* __restrict__ vt,
    const unsigned short* __restrict__ rkb, const float* __restrict__ mask,
    unsigned short* __restrict__ attnb) {
  __shared__ unsigned short Ks[64 * 64];
  __shared__ unsigned short Vs[64 * 64];
  __shared__ unsigned short Rs[128 * 64];
  __shared__ unsigned short Ps[4][16 * 72];
  __shared__ float Bnd[4][16 * 83];

  const int tid = threadIdx.x;
  const int w = tid >> 6, lane = tid & 63;
  const int quad = lane >> 4, li = lane & 15;
  const int qt = blockIdx.x, h = blockIdx.y, b = blockIdx.z;
  const int t0blk = qt * 64;
  const int t0w = t0blk + w * 16;
  const int rboff = 48 - 16 * w;

  bf16x8 aqw[2], aqr[2];
  {
    const unsigned short* p1 = qw + ((size_t)((b * Tq + t0w + li) * Hh + h)) * 64;
    aqw[0] = *(const bf16x8*)(p1 + quad * 8);
    aqw[1] = *(const bf16x8*)(p1 + 32 + quad * 8);
    const unsigned short* p2 = qr + ((size_t)((b * Tq + t0w + li) * Hh + h)) * 64;
    aqr[0] = *(const bf16x8*)(p2 + quad * 8);
    aqr[1] = *(const bf16x8*)(p2 + 32 + quad * 8);
  }

  f32x4 z = {0.f, 0.f, 0.f, 0.f};
  f32x4 o[4];
  o[0] = z; o[1] = z; o[2] = z; o[3] = z;
  float mrow[4] = {-3e38f, -3e38f, -3e38f, -3e38f};
  float lrow[4] = {0.f, 0.f, 0.f, 0.f};

  const int srow = lane >> 3;
  const int scs = lane & 7;
  const float SC = 0.125f * 1.4426950408889634f;
  const float BIG = 1e30f * 1.4426950408889634f;

  for (int jt = 0; jt < 32; ++jt) {
    const int j0 = jt * 64;
    __syncthreads();
#pragma unroll
    for (int s = 0; s < 2; ++s) {
      int i = w * 2 + s;
      int r = i * 8 + srow;
      int c = scs ^ (r & 7);
      gl2lds16(kb + ((size_t)((b * Ll + j0 + r) * Hh + h)) * 64 + c * 8,
               (char*)Ks + i * 1024);
      gl2lds16(vt + ((size_t)((b * Hh + h) * 64 + r)) * Ll + j0 + c * 8,
               (char*)Vs + i * 1024);
    }
    const int rbase = Tq - t0blk - 63 + j0;
#pragma unroll
    for (int s = 0; s < 4; ++s) {
      int i = w * 4 + s;
      int r = i * 8 + srow;
      int gr = rbase + r;
      if (gr > Rr - 1) gr = Rr - 1;
      int c = scs ^ (r & 7);
      gl2lds16(rkb + ((size_t)gr * Hh + h) * 64 + c * 8, (char*)Rs + i * 1024);
    }
    __syncthreads();

    // content scores: S_c[t'][j'] via qw . K
    f32x4 sc[4];
    sc[0] = z; sc[1] = z; sc[2] = z; sc[3] = z;
#pragma unroll
    for (int ks = 0; ks < 2; ++ks)
#pragma unroll
      for (int nt = 0; nt < 4; ++nt) {
        int j = nt * 16 + li;
        int ch = (ks * 4 + quad) ^ (j & 7);
        bf16x8 kf = *(const bf16x8*)((const char*)Ks + j * 128 + ch * 16);
        sc[nt] = __builtin_amdgcn_mfma_f32_16x16x32_bf16(aqw[ks], kf, sc[nt], 0, 0, 0);
      }
    // band scores: band[t'][c] = qr . rk[rbase + rboff + c]
    f32x4 bd[5];
    bd[0] = z; bd[1] = z; bd[2] = z; bd[3] = z; bd[4] = z;
#pragma unroll
    for (int ks = 0; ks < 2; ++ks)
#pragma unroll
      for (int nt = 0; nt < 5; ++nt) {
        int r = rboff + nt * 16 + li;
        int ch = (ks * 4 + quad) ^ (r & 7);
        bf16x8 rf = *(const bf16x8*)((const char*)Rs + r * 128 + ch * 16);
        bd[nt] = __builtin_amdgcn_mfma_f32_16x16x32_bf16(aqr[ks], rf, bd[nt], 0, 0, 0);
      }
    // band -> per-wave LDS (fp32), then diagonal extract: c = j' + 15 - t'
    float* bw = &Bnd[w][0];
#pragma unroll
    for (int nt = 0; nt < 5; ++nt)
#pragma unroll
      for (int reg = 0; reg < 4; ++reg)
        bw[(quad * 4 + reg) * 83 + nt * 16 + li] = bd[nt][reg];
    __builtin_amdgcn_s_waitcnt(0xc07f);

    float sv[4][4];
#pragma unroll
    for (int nt = 0; nt < 4; ++nt)
#pragma unroll
      for (int reg = 0; reg < 4; ++reg) {
        int row = quad * 4 + reg;
        int cbd = nt * 16 + li + 15 - row;
        float rel = bw[row * 83 + cbd];
        float mval = mask[((size_t)(b * Tq + t0w + row)) * Ll + j0 + nt * 16 + li];
        sv[nt][reg] = (sc[nt][reg] + rel) * SC - (1.0f - mval) * BIG;
      }
    // online softmax (log2 domain), rows live across 16-lane groups
    float pbuf[4][4];
    float alpha[4];
#pragma unroll
    for (int reg = 0; reg < 4; ++reg) {
      float vmx = fmaxf(fmaxf(sv[0][reg], sv[1][reg]), fmaxf(sv[2][reg], sv[3][reg]));
      vmx = fmaxf(vmx, __shfl_xor(vmx, 1));
      vmx = fmaxf(vmx, __shfl_xor(vmx, 2));
      vmx = fmaxf(vmx, __shfl_xor(vmx, 4));
      vmx = fmaxf(vmx, __shfl_xor(vmx, 8));
      float mn = fmaxf(mrow[reg], vmx);
      float a = exp2f(mrow[reg] - mn);
      float ssum = 0.f;
#pragma unroll
      for (int nt = 0; nt < 4; ++nt) {
        float p = exp2f(sv[nt][reg] - mn);
        pbuf[nt][reg] = p;
        ssum += p;
      }
      ssum += __shfl_xor(ssum, 1);
      ssum += __shfl_xor(ssum, 2);
      ssum += __shfl_xor(ssum, 4);
      ssum += __shfl_xor(ssum, 8);
      lrow[reg] = lrow[reg] * a + ssum;
      mrow[reg] = mn;
      alpha[reg] = a;
    }
#pragma unroll
    for (int nt = 0; nt < 4; ++nt) {
      o[nt][0] *= alpha[0];
      o[nt][1] *= alpha[1];
      o[nt][2] *= alpha[2];
      o[nt][3] *= alpha[3];
    }
    // P -> per-wave LDS bf16 (C-layout -> A-operand layout round trip)
    unsigned short* pw = &Ps[w][0];
#pragma unroll
    for (int nt = 0; nt < 4; ++nt)
#pragma unroll
      for (int reg = 0; reg < 4; ++reg)
        pw[(quad * 4 + reg) * 72 + nt * 16 + li] = f2bf(pbuf[nt][reg]);
    __builtin_amdgcn_s_waitcnt(0xc07f);
    // PV
#pragma unroll
    for (int ks = 0; ks < 2; ++ks) {
      bf16x8 ap = *(const bf16x8*)(pw + li * 72 + ks * 32 + quad * 8);
#pragma unroll
      for (int nt = 0; nt < 4; ++nt) {
        int dv = nt * 16 + li;
        int ch = (ks * 4 + quad) ^ (dv & 7);
        bf16x8 vf = *(const bf16x8*)((const char*)Vs + dv * 128 + ch * 16);
        o[nt] = __builtin_amdgcn_mfma_f32_16x16x32_bf16(ap, vf, o[nt], 0, 0, 0);
      }
    }
  }
  // epilogue: attn[b,t,h,dv] = O / l  (bf16 for the output GEMM)
#pragma unroll
  for (int nt = 0; nt < 4; ++nt)
#pragma unroll
    for (int reg = 0; reg < 4; ++reg) {
      int row = t0w + quad * 4 + reg;
      int col = h * 64 + nt * 16 + li;
      attnb[((size_t)(b * Tq + row)) * 1024 + col] = f2bf(o[nt][reg] / lrow[reg]);
    }
}

extern "C" void kernel_launch(void* const* d_in, const int* in_sizes, int n_in,
                              void* d_out, int out_size, void* d_ws, size_t ws_size,
                              hipStream_t stream) {
  const float* x = (const float*)d_in[0];
  const float* mask = (const float*)d_in[1];
  const float* pos = (const float*)d_in[2];
  const float* mem = (const float*)d_in[3];
  const float* Wq = (const float*)d_in[4];
  const float* Wk = (const float*)d_in[5];
  const float* Wv = (const float*)d_in[6];
  const float* Wr = (const float*)d_in[7];
  const float* rwb = (const float*)d_in[8];
  const float* rrb = (const float*)d_in[9];
  const float* Wo = (const float*)d_in[10];
  float* out = (float*)d_out;

  uint8_t* ws = (uint8_t*)d_ws;
  const size_t MB = 1024 * 1024;
  unsigned short* Vinb = (unsigned short*)(ws + 0);        // 8 MB  [4096][1024]
  unsigned short* WqT = (unsigned short*)(ws + 8 * MB);    // 2 MB
  unsigned short* WkT = (unsigned short*)(ws + 10 * MB);   // 2 MB
  unsigned short* WvT = (unsigned short*)(ws + 12 * MB);   // 2 MB
  unsigned short* WrT = (unsigned short*)(ws + 14 * MB);   // 2 MB
  unsigned short* WoT = (unsigned short*)(ws + 16 * MB);   // 2 MB
  unsigned short* Pb = (unsigned short*)(ws + 18 * MB);    // 6 MB  [3072][1024]
  unsigned short* qwb = (unsigned short*)(ws + 24 * MB);   // 4 MB  [2048][1024]
  unsigned short* qrb = (unsigned short*)(ws + 28 * MB);   // 4 MB
  unsigned short* kb = (unsigned short*)(ws + 32 * MB);    // 8 MB  [4096][1024]
  unsigned short* vb = (unsigned short*)(ws + 40 * MB);    // 8 MB
  unsigned short* vtb = (unsigned short*)(ws + 48 * MB);   // 8 MB  [B][H][64][2048]
  unsigned short* rkb = (unsigned short*)(ws + 56 * MB);   // 6 MB  [3072][1024]
  unsigned short* attnb = (unsigned short*)(ws + 62 * MB); // 4 MB  [2048][1024]

  hipLaunchKernelGGL(k_vin, dim3(4096), dim3(256), 0, stream, x, mem, Vinb);
  hipLaunchKernelGGL(k_castp, dim3(3072), dim3(256), 0, stream, pos, Pb);
  hipLaunchKernelGGL(k_wtall, dim3(16, 16, 5), dim3(256), 0, stream,
                     Wq, Wk, Wv, Wr, Wo, WqT, WkT, WvT, WrT, WoT);
  hipLaunchKernelGGL(k_gemm_q, dim3(16, 8), dim3(256), 0, stream,
                     Vinb, WqT, rwb, rrb, qwb, qrb);
  hipLaunchKernelGGL(k_gemm_kv, dim3(32, 16), dim3(256), 0, stream,
                     Vinb, WkT, WvT, kb, vb);
  hipLaunchKernelGGL(k_vt, dim3(2048), dim3(256), 0, stream, vb, vtb);
  hipLaunchKernelGGL(k_gemm_rk, dim3(24, 8), dim3(256), 0, stream, Pb, WrT, rkb);
  hipLaunchKernelGGL(k_attn, dim3(16, 16, 2), dim3(256), 0, stream,
                     qwb, qrb, kb, vtb, rkb, mask, attnb);
  hipLaunchKernelGGL(k_gemm_out, dim3(16, 8), dim3(256), 0, stream,
                     attnb, WoT, out);
}

// Round 2
// 302.289 us; speedup vs baseline: 1.0546x; 1.0546x over previous
//
#include <hip/hip_runtime.h>
#include <stdint.h>

#define Bz 2
#define Tq 1024
#define Mm 1024
#define Hh 16
#define Ll 2048
#define Rr 3072

typedef __attribute__((ext_vector_type(8))) short bf16x8;
typedef __attribute__((ext_vector_type(4))) float f32x4;

typedef __attribute__((address_space(3))) uint8_t lds_u8_t;
typedef __attribute__((address_space(1))) uint8_t glb_u8_t;

__device__ __forceinline__ void gl2lds16(const void* g, void* l) {
  __builtin_amdgcn_global_load_lds((const glb_u8_t*)g, (lds_u8_t*)l, 16, 0, 0);
}

__device__ __forceinline__ unsigned short f2bf(float f) {
  unsigned int u = __builtin_bit_cast(unsigned int, f);
  u = u + 0x7fffu + ((u >> 16) & 1u);
  return (unsigned short)(u >> 16);
}

// ---------------- prep: concat+cast values, cast pos (merged) ---------------
__global__ __launch_bounds__(256) void k_prep(const float* __restrict__ x,
                                              const float* __restrict__ mem,
                                              const float* __restrict__ pos,
                                              unsigned short* __restrict__ vin,
                                              unsigned short* __restrict__ pb) {
  int bid = blockIdx.x;
  if (bid < 4096) {
    int idx = bid * 256 + threadIdx.x;
    int e = idx << 2;
    int row = e >> 10, col = e & 1023;
    int b = row >> 11, l = row & 2047;
    const float* s = (l < Mm) ? (mem + (((size_t)b * Mm + l) << 10) + col)
                              : (x + (((size_t)b * Tq + (l - Mm)) << 10) + col);
    float4 v = *(const float4*)s;
    ushort4 o;
    o.x = f2bf(v.x); o.y = f2bf(v.y); o.z = f2bf(v.z); o.w = f2bf(v.w);
    *(ushort4*)(vin + e) = o;
  } else {
    int idx = (bid - 4096) * 256 + threadIdx.x;
    int e = idx << 2;
    float4 v = *(const float4*)(pos + e);
    ushort4 t;
    t.x = f2bf(v.x); t.y = f2bf(v.y); t.z = f2bf(v.z); t.w = f2bf(v.w);
    *(ushort4*)(pb + e) = t;
  }
}

// ---------------- prep: transpose-cast 5 weight matrices (1024x1024) --------
__global__ __launch_bounds__(256) void k_wtall(
    const float* __restrict__ w0, const float* __restrict__ w1,
    const float* __restrict__ w2, const float* __restrict__ w3,
    const float* __restrict__ w4,
    unsigned short* __restrict__ t0, unsigned short* __restrict__ t1,
    unsigned short* __restrict__ t2, unsigned short* __restrict__ t3,
    unsigned short* __restrict__ t4) {
  const float* W;
  unsigned short* WT;
  switch (blockIdx.z) {
    case 0: W = w0; WT = t0; break;
    case 1: W = w1; WT = t1; break;
    case 2: W = w2; WT = t2; break;
    case 3: W = w3; WT = t3; break;
    default: W = w4; WT = t4; break;
  }
  __shared__ float tile[64][65];
  int k0 = blockIdx.x * 64, n0 = blockIdx.y * 64;
  int tid = threadIdx.x;
  int rr = tid >> 4, c4 = (tid & 15) * 4;
#pragma unroll
  for (int it = 0; it < 4; ++it) {
    int r = rr + it * 16;
    float4 v = *(const float4*)(W + (size_t)(k0 + r) * 1024 + n0 + c4);
    tile[r][c4] = v.x; tile[r][c4 + 1] = v.y;
    tile[r][c4 + 2] = v.z; tile[r][c4 + 3] = v.w;
  }
  __syncthreads();
#pragma unroll
  for (int it = 0; it < 4; ++it) {
    int n = rr + it * 16;
    ushort4 o;
    o.x = f2bf(tile[c4 + 0][n]); o.y = f2bf(tile[c4 + 1][n]);
    o.z = f2bf(tile[c4 + 2][n]); o.w = f2bf(tile[c4 + 3][n]);
    *(ushort4*)(WT + (size_t)(n0 + n) * 1024 + k0 + c4) = o;
  }
}

// ---------------- bf16 NT GEMM core (m97 structure, K=1024) -----------------
template <int RMAP>
__device__ __forceinline__ void gemm_core(const unsigned short* __restrict__ A,
                                          const unsigned short* __restrict__ Bt,
                                          int m0, int n0, unsigned short* As,
                                          unsigned short* Bs, f32x4 acc[4][4]) {
  const int tid = threadIdx.x;
  const int w = tid >> 6, lane = tid & 63;
  const int quad = lane >> 4, li = lane & 15;
  const int wr = w >> 1, wc = w & 1;
  f32x4 z = {0.f, 0.f, 0.f, 0.f};
#pragma unroll
  for (int mi = 0; mi < 4; ++mi)
#pragma unroll
    for (int ni = 0; ni < 4; ++ni) acc[mi][ni] = z;

  const int rs = lane >> 2;
  const int cs = lane & 3;

  for (int k0 = 0; k0 < 1024; k0 += 32) {
    __syncthreads();
#pragma unroll
    for (int s = 0; s < 2; ++s) {
      int i = w * 2 + s;
      int r = i * 16 + rs;
      int c = cs ^ ((r >> 1) & 3);
      int ar = m0 + r;
      if (RMAP) ar = ar + 1024 + (ar & 1024);
      gl2lds16(A + (size_t)ar * 1024 + k0 + c * 8, (char*)As + i * 1024);
      int br = n0 + r;
      gl2lds16(Bt + (size_t)br * 1024 + k0 + c * 8, (char*)Bs + i * 1024);
    }
    __syncthreads();
    bf16x8 af[4], bfr[4];
#pragma unroll
    for (int mi = 0; mi < 4; ++mi) {
      int r = wr * 64 + mi * 16 + li;
      int ch = quad ^ ((r >> 1) & 3);
      af[mi] = *(const bf16x8*)((const char*)As + r * 64 + ch * 16);
    }
#pragma unroll
    for (int ni = 0; ni < 4; ++ni) {
      int r = wc * 64 + ni * 16 + li;
      int ch = quad ^ ((r >> 1) & 3);
      bfr[ni] = *(const bf16x8*)((const char*)Bs + r * 64 + ch * 16);
    }
#pragma unroll
    for (int mi = 0; mi < 4; ++mi)
#pragma unroll
      for (int ni = 0; ni < 4; ++ni)
        acc[mi][ni] = __builtin_amdgcn_mfma_f32_16x16x32_bf16(
            af[mi], bfr[ni], acc[mi][ni], 0, 0, 0);
  }
}

// fused q (dual-bias out) | k | v | rk projections; 1D tile grid of 832
__global__ __launch_bounds__(256) void k_proj(
    const unsigned short* __restrict__ Vin, const unsigned short* __restrict__ Pb,
    const unsigned short* __restrict__ WqT, const unsigned short* __restrict__ WkT,
    const unsigned short* __restrict__ WvT, const unsigned short* __restrict__ WrT,
    const float* __restrict__ rwb, const float* __restrict__ rrb,
    unsigned short* __restrict__ qwb, unsigned short* __restrict__ qrb,
    unsigned short* __restrict__ kb, unsigned short* __restrict__ vb,
    unsigned short* __restrict__ rkb) {
  __shared__ unsigned short As[128 * 32];
  __shared__ unsigned short Bs[128 * 32];
  const int t = blockIdx.x;
  const int tid = threadIdx.x, w = tid >> 6, lane = tid & 63;
  const int quad = lane >> 4, li = lane & 15, wr = w >> 1, wc = w & 1;
  f32x4 acc[4][4];

  if (t < 512) {  // k (0..255) or v (256..511): M=4096, N=1024
    int tt = t & 255;
    int m0 = (tt >> 3) * 128, n0 = (tt & 7) * 128;
    const unsigned short* Bt = (t < 256) ? WkT : WvT;
    unsigned short* C = (t < 256) ? kb : vb;
    gemm_core<0>(Vin, Bt, m0, n0, As, Bs, acc);
#pragma unroll
    for (int mi = 0; mi < 4; ++mi)
#pragma unroll
      for (int ni = 0; ni < 4; ++ni)
#pragma unroll
        for (int reg = 0; reg < 4; ++reg) {
          int rrow = m0 + wr * 64 + mi * 16 + quad * 4 + reg;
          int cc = n0 + wc * 64 + ni * 16 + li;
          C[(size_t)rrow * 1024 + cc] = f2bf(acc[mi][ni][reg]);
        }
  } else if (t < 640) {  // q dual: M=2048 (input rows), N=1024
    int tt = t - 512;
    int m0 = (tt >> 3) * 128, n0 = (tt & 7) * 128;
    gemm_core<1>(Vin, WqT, m0, n0, As, Bs, acc);
#pragma unroll
    for (int mi = 0; mi < 4; ++mi)
#pragma unroll
      for (int ni = 0; ni < 4; ++ni) {
        int cc = n0 + wc * 64 + ni * 16 + li;
        float bw_ = rwb[cc], br_ = rrb[cc];
#pragma unroll
        for (int reg = 0; reg < 4; ++reg) {
          int rrow = m0 + wr * 64 + mi * 16 + quad * 4 + reg;
          size_t off = (size_t)rrow * 1024 + cc;
          qwb[off] = f2bf(acc[mi][ni][reg] + bw_);
          qrb[off] = f2bf(acc[mi][ni][reg] + br_);
        }
      }
  } else {  // rk: M=3072, N=1024
    int tt = t - 640;
    int m0 = (tt >> 3) * 128, n0 = (tt & 7) * 128;
    gemm_core<0>(Pb, WrT, m0, n0, As, Bs, acc);
#pragma unroll
    for (int mi = 0; mi < 4; ++mi)
#pragma unroll
      for (int ni = 0; ni < 4; ++ni)
#pragma unroll
        for (int reg = 0; reg < 4; ++reg) {
          int rrow = m0 + wr * 64 + mi * 16 + quad * 4 + reg;
          int cc = n0 + wc * 64 + ni * 16 + li;
          rkb[(size_t)rrow * 1024 + cc] = f2bf(acc[mi][ni][reg]);
        }
  }
}

// output projection, 64x128 tile (256 blocks), fp32 out -> d_out
__global__ __launch_bounds__(256) void k_gemm_out64(
    const unsigned short* __restrict__ attnb, const unsigned short* __restrict__ WoT,
    float* __restrict__ out) {
  __shared__ unsigned short As[64 * 32];
  __shared__ unsigned short Bs[128 * 32];
  int m0 = blockIdx.x * 64, n0 = blockIdx.y * 128;
  const int tid = threadIdx.x, w = tid >> 6, lane = tid & 63;
  const int quad = lane >> 4, li = lane & 15, wr = w >> 1, wc = w & 1;
  f32x4 z = {0.f, 0.f, 0.f, 0.f};
  f32x4 acc[2][4];
#pragma unroll
  for (int mi = 0; mi < 2; ++mi)
#pragma unroll
    for (int ni = 0; ni < 4; ++ni) acc[mi][ni] = z;
  const int rs = lane >> 2, cs = lane & 3;
  for (int k0 = 0; k0 < 1024; k0 += 32) {
    __syncthreads();
    {
      int r = w * 16 + rs;
      int c = cs ^ ((r >> 1) & 3);
      gl2lds16(attnb + (size_t)(m0 + r) * 1024 + k0 + c * 8, (char*)As + w * 1024);
    }
#pragma unroll
    for (int s = 0; s < 2; ++s) {
      int i = w * 2 + s;
      int r = i * 16 + rs;
      int c = cs ^ ((r >> 1) & 3);
      gl2lds16(WoT + (size_t)(n0 + r) * 1024 + k0 + c * 8, (char*)Bs + i * 1024);
    }
    __syncthreads();
    bf16x8 af[2], bfr[4];
#pragma unroll
    for (int mi = 0; mi < 2; ++mi) {
      int r = wr * 32 + mi * 16 + li;
      int ch = quad ^ ((r >> 1) & 3);
      af[mi] = *(const bf16x8*)((const char*)As + r * 64 + ch * 16);
    }
#pragma unroll
    for (int ni = 0; ni < 4; ++ni) {
      int r = wc * 64 + ni * 16 + li;
      int ch = quad ^ ((r >> 1) & 3);
      bfr[ni] = *(const bf16x8*)((const char*)Bs + r * 64 + ch * 16);
    }
#pragma unroll
    for (int mi = 0; mi < 2; ++mi)
#pragma unroll
      for (int ni = 0; ni < 4; ++ni)
        acc[mi][ni] = __builtin_amdgcn_mfma_f32_16x16x32_bf16(
            af[mi], bfr[ni], acc[mi][ni], 0, 0, 0);
  }
#pragma unroll
  for (int mi = 0; mi < 2; ++mi)
#pragma unroll
    for (int ni = 0; ni < 4; ++ni)
#pragma unroll
      for (int reg = 0; reg < 4; ++reg) {
        int rrow = m0 + wr * 32 + mi * 16 + quad * 4 + reg;
        int cc = n0 + wc * 64 + ni * 16 + li;
        out[(size_t)rrow * 1024 + cc] = acc[mi][ni][reg];
      }
}

// ---------------- v transpose: vb[b,l,h,dv] -> vt[b,h,dv,l] -----------------
__global__ __launch_bounds__(256) void k_vt(const unsigned short* __restrict__ vb,
                                            unsigned short* __restrict__ vt) {
  int id = blockIdx.x * 256 + threadIdx.x;
  int bh = id >> 14;
  int rem = id & 16383;
  int lc = rem >> 6, dv = rem & 63;
  int b = bh >> 4, h = bh & 15;
  int l0 = lc * 8;
  unsigned short tmp[8];
#pragma unroll
  for (int e = 0; e < 8; ++e)
    tmp[e] = vb[((size_t)((b * Ll + l0 + e) * Hh + h)) * 64 + dv];
  ushort4 o1 = {tmp[0], tmp[1], tmp[2], tmp[3]};
  ushort4 o2 = {tmp[4], tmp[5], tmp[6], tmp[7]};
  unsigned short* dst = vt + ((size_t)(bh * 64 + dv)) * Ll + l0;
  *(ushort4*)(dst) = o1;
  *(ushort4*)(dst + 4) = o2;
}

// ---------------- flash attention with TXL relative shift, kv-split=2 -------
// grid (T/64, H, B*2); per block: 64 q rows, 1024 keys (split half).
// Writes unnormalized partial O + per-row m,l; k_combine merges halves.
// LDS = 8K(Ks)+8K(Vs)+16K(Rs)+21.25K(Bnd, P overlaid) = 54016 B -> 3 blocks/CU.
__global__ __launch_bounds__(256, 3) void k_attn(
    const unsigned short* __restrict__ qw, const unsigned short* __restrict__ qr,
    const unsigned short* __restrict__ kb, const unsigned short* __restrict__ vt,
    const unsigned short* __restrict__ rkb, const float* __restrict__ mask,
    float* __restrict__ po, float* __restrict__ pm, float* __restrict__ pl) {
  __shared__ unsigned short Ks[64 * 64];
  __shared__ unsigned short Vs[64 * 64];
  __shared__ unsigned short Rs[128 * 64];
  __shared__ float Bnd[4][16 * 83];  // P (bf16, stride 72) overlaid per-wave

  const int tid = threadIdx.x;
  const int w = tid >> 6, lane = tid & 63;
  const int quad = lane >> 4, li = lane & 15;
  const int qt = blockIdx.x, h = blockIdx.y;
  const int b = blockIdx.z >> 1, split = blockIdx.z & 1;
  const int t0blk = qt * 64;
  const int t0w = t0blk + w * 16;
  const int rboff = 48 - 16 * w;

  bf16x8 aqw[2], aqr[2];
  {
    const unsigned short* p1 = qw + ((size_t)((b * Tq + t0w + li) * Hh + h)) * 64;
    aqw[0] = *(const bf16x8*)(p1 + quad * 8);
    aqw[1] = *(const bf16x8*)(p1 + 32 + quad * 8);
    const unsigned short* p2 = qr + ((size_t)((b * Tq + t0w + li) * Hh + h)) * 64;
    aqr[0] = *(const bf16x8*)(p2 + quad * 8);
    aqr[1] = *(const bf16x8*)(p2 + 32 + quad * 8);
  }

  f32x4 z = {0.f, 0.f, 0.f, 0.f};
  f32x4 o[4];
  o[0] = z; o[1] = z; o[2] = z; o[3] = z;
  float mrow[4] = {-3e38f, -3e38f, -3e38f, -3e38f};
  float lrow[4] = {0.f, 0.f, 0.f, 0.f};

  const int srow = lane >> 3;
  const int scs = lane & 7;
  const float SC = 0.125f * 1.4426950408889634f;
  const float BIG = 1e30f * 1.4426950408889634f;

  for (int jt = 0; jt < 16; ++jt) {
    const int j0 = (split << 10) + jt * 64;
    __syncthreads();
#pragma unroll
    for (int s = 0; s < 2; ++s) {
      int i = w * 2 + s;
      int r = i * 8 + srow;
      int c = scs ^ (r & 7);
      gl2lds16(kb + ((size_t)((b * Ll + j0 + r) * Hh + h)) * 64 + c * 8,
               (char*)Ks + i * 1024);
      gl2lds16(vt + ((size_t)((b * Hh + h) * 64 + r)) * Ll + j0 + c * 8,
               (char*)Vs + i * 1024);
    }
    const int rbase = Tq - t0blk - 63 + j0;
#pragma unroll
    for (int s = 0; s < 4; ++s) {
      int i = w * 4 + s;
      int r = i * 8 + srow;
      int gr = rbase + r;
      if (gr > Rr - 1) gr = Rr - 1;
      int c = scs ^ (r & 7);
      gl2lds16(rkb + ((size_t)gr * Hh + h) * 64 + c * 8, (char*)Rs + i * 1024);
    }
    __syncthreads();

    // content scores
    f32x4 sc[4];
    sc[0] = z; sc[1] = z; sc[2] = z; sc[3] = z;
#pragma unroll
    for (int ks = 0; ks < 2; ++ks)
#pragma unroll
      for (int nt = 0; nt < 4; ++nt) {
        int j = nt * 16 + li;
        int ch = (ks * 4 + quad) ^ (j & 7);
        bf16x8 kf = *(const bf16x8*)((const char*)Ks + j * 128 + ch * 16);
        sc[nt] = __builtin_amdgcn_mfma_f32_16x16x32_bf16(aqw[ks], kf, sc[nt], 0, 0, 0);
      }
    // band scores
    f32x4 bd[5];
    bd[0] = z; bd[1] = z; bd[2] = z; bd[3] = z; bd[4] = z;
#pragma unroll
    for (int ks = 0; ks < 2; ++ks)
#pragma unroll
      for (int nt = 0; nt < 5; ++nt) {
        int r = rboff + nt * 16 + li;
        int ch = (ks * 4 + quad) ^ (r & 7);
        bf16x8 rf = *(const bf16x8*)((const char*)Rs + r * 128 + ch * 16);
        bd[nt] = __builtin_amdgcn_mfma_f32_16x16x32_bf16(aqr[ks], rf, bd[nt], 0, 0, 0);
      }
    float* bw = &Bnd[w][0];
#pragma unroll
    for (int nt = 0; nt < 5; ++nt)
#pragma unroll
      for (int reg = 0; reg < 4; ++reg)
        bw[(quad * 4 + reg) * 83 + nt * 16 + li] = bd[nt][reg];
    __builtin_amdgcn_s_waitcnt(0xc07f);

    float sv[4][4];
#pragma unroll
    for (int nt = 0; nt < 4; ++nt)
#pragma unroll
      for (int reg = 0; reg < 4; ++reg) {
        int row = quad * 4 + reg;
        int cbd = nt * 16 + li + 15 - row;
        float rel = bw[row * 83 + cbd];
        float mval = mask[((size_t)(b * Tq + t0w + row)) * Ll + j0 + nt * 16 + li];
        sv[nt][reg] = (sc[nt][reg] + rel) * SC - (1.0f - mval) * BIG;
      }
    float pbuf[4][4];
    float alpha[4];
#pragma unroll
    for (int reg = 0; reg < 4; ++reg) {
      float vmx = fmaxf(fmaxf(sv[0][reg], sv[1][reg]), fmaxf(sv[2][reg], sv[3][reg]));
      vmx = fmaxf(vmx, __shfl_xor(vmx, 1));
      vmx = fmaxf(vmx, __shfl_xor(vmx, 2));
      vmx = fmaxf(vmx, __shfl_xor(vmx, 4));
      vmx = fmaxf(vmx, __shfl_xor(vmx, 8));
      float mn = fmaxf(mrow[reg], vmx);
      float a = exp2f(mrow[reg] - mn);
      float ssum = 0.f;
#pragma unroll
      for (int nt = 0; nt < 4; ++nt) {
        float p = exp2f(sv[nt][reg] - mn);
        pbuf[nt][reg] = p;
        ssum += p;
      }
      ssum += __shfl_xor(ssum, 1);
      ssum += __shfl_xor(ssum, 2);
      ssum += __shfl_xor(ssum, 4);
      ssum += __shfl_xor(ssum, 8);
      lrow[reg] = lrow[reg] * a + ssum;
      mrow[reg] = mn;
      alpha[reg] = a;
    }
#pragma unroll
    for (int nt = 0; nt < 4; ++nt) {
      o[nt][0] *= alpha[0];
      o[nt][1] *= alpha[1];
      o[nt][2] *= alpha[2];
      o[nt][3] *= alpha[3];
    }
    // compiler fence: P (ushort) overlays Bnd (float) — forbid reordering of
    // the band reads above vs the P writes below (HW LDS pipe is in-order).
    asm volatile("" ::: "memory");
    unsigned short* pw = (unsigned short*)&Bnd[w][0];
#pragma unroll
    for (int nt = 0; nt < 4; ++nt)
#pragma unroll
      for (int reg = 0; reg < 4; ++reg)
        pw[(quad * 4 + reg) * 72 + nt * 16 + li] = f2bf(pbuf[nt][reg]);
    __builtin_amdgcn_s_waitcnt(0xc07f);
#pragma unroll
    for (int ks = 0; ks < 2; ++ks) {
      bf16x8 ap = *(const bf16x8*)(pw + li * 72 + ks * 32 + quad * 8);
#pragma unroll
      for (int nt = 0; nt < 4; ++nt) {
        int dv = nt * 16 + li;
        int ch = (ks * 4 + quad) ^ (dv & 7);
        bf16x8 vf = *(const bf16x8*)((const char*)Vs + dv * 128 + ch * 16);
        o[nt] = __builtin_amdgcn_mfma_f32_16x16x32_bf16(ap, vf, o[nt], 0, 0, 0);
      }
    }
  }
  // epilogue: unnormalized partials
  const int bs = (b * 2 + split) * 16 + h;
#pragma unroll
  for (int nt = 0; nt < 4; ++nt)
#pragma unroll
    for (int reg = 0; reg < 4; ++reg) {
      int trow = t0w + quad * 4 + reg;
      po[((size_t)bs * 1024 + trow) * 64 + nt * 16 + li] = o[nt][reg];
    }
  if (li == 0) {
#pragma unroll
    for (int reg = 0; reg < 4; ++reg) {
      int trow = t0w + quad * 4 + reg;
      pm[(size_t)bs * 1024 + trow] = mrow[reg];
      pl[(size_t)bs * 1024 + trow] = lrow[reg];
    }
  }
}

// ---------------- combine the two kv-split halves -> attnb (bf16) -----------
__global__ __launch_bounds__(256) void k_combine(
    const float* __restrict__ po, const float* __restrict__ pm,
    const float* __restrict__ pl, unsigned short* __restrict__ attnb) {
  int id = blockIdx.x * 256 + threadIdx.x;  // 524288 total
  int dv4 = (id & 15) << 2;
  int t = (id >> 4) & 1023;
  int h = (id >> 14) & 15;
  int b = id >> 18;
  size_t r0 = ((size_t)((b * 2 + 0) * 16 + h)) * 1024 + t;
  size_t r1 = ((size_t)((b * 2 + 1) * 16 + h)) * 1024 + t;
  float m0 = pm[r0], m1 = pm[r1];
  float l0 = pl[r0], l1 = pl[r1];
  float mx = fmaxf(m0, m1);
  float w0 = exp2f(m0 - mx), w1 = exp2f(m1 - mx);
  float inv = 1.0f / (l0 * w0 + l1 * w1);
  float4 o0 = *(const float4*)(po + r0 * 64 + dv4);
  float4 o1 = *(const float4*)(po + r1 * 64 + dv4);
  ushort4 res;
  res.x = f2bf((o0.x * w0 + o1.x * w1) * inv);
  res.y = f2bf((o0.y * w0 + o1.y * w1) * inv);
  res.z = f2bf((o0.z * w0 + o1.z * w1) * inv);
  res.w = f2bf((o0.w * w0 + o1.w * w1) * inv);
  *(ushort4*)(attnb + ((size_t)(b * 1024 + t)) * 1024 + h * 64 + dv4) = res;
}

extern "C" void kernel_launch(void* const* d_in, const int* in_sizes, int n_in,
                              void* d_out, int out_size, void* d_ws, size_t ws_size,
                              hipStream_t stream) {
  const float* x = (const float*)d_in[0];
  const float* mask = (const float*)d_in[1];
  const float* pos = (const float*)d_in[2];
  const float* mem = (const float*)d_in[3];
  const float* Wq = (const float*)d_in[4];
  const float* Wk = (const float*)d_in[5];
  const float* Wv = (const float*)d_in[6];
  const float* Wr = (const float*)d_in[7];
  const float* rwb = (const float*)d_in[8];
  const float* rrb = (const float*)d_in[9];
  const float* Wo = (const float*)d_in[10];
  float* out = (float*)d_out;

  uint8_t* ws = (uint8_t*)d_ws;
  const size_t MB = 1024 * 1024;
  unsigned short* Vinb = (unsigned short*)(ws + 0);        // 8 MB (dead post-proj)
  unsigned short* WqT = (unsigned short*)(ws + 8 * MB);    // 2 MB (dead post-proj)
  unsigned short* WkT = (unsigned short*)(ws + 10 * MB);   // 2 MB
  unsigned short* WvT = (unsigned short*)(ws + 12 * MB);   // 2 MB
  unsigned short* WrT = (unsigned short*)(ws + 14 * MB);   // 2 MB
  unsigned short* WoT = (unsigned short*)(ws + 16 * MB);   // 2 MB (live to end)
  unsigned short* Pb = (unsigned short*)(ws + 18 * MB);    // 6 MB (dead post-proj)
  unsigned short* qwb = (unsigned short*)(ws + 24 * MB);   // 4 MB
  unsigned short* qrb = (unsigned short*)(ws + 28 * MB);   // 4 MB
  unsigned short* kb = (unsigned short*)(ws + 32 * MB);    // 8 MB
  unsigned short* vb = (unsigned short*)(ws + 40 * MB);    // 8 MB
  unsigned short* vtb = (unsigned short*)(ws + 48 * MB);   // 8 MB
  unsigned short* rkb = (unsigned short*)(ws + 56 * MB);   // 6 MB
  unsigned short* attnb = (unsigned short*)(ws + 62 * MB); // 4 MB
  // overlays (written by k_attn, after the above are dead):
  float* po = (float*)(ws + 0);                            // 16 MB [b,s,h,t,dv]
  float* pm = (float*)(ws + 18 * MB);                      // 256 KB
  float* pl = (float*)(ws + 19 * MB);                      // 256 KB

  hipLaunchKernelGGL(k_prep, dim3(7168), dim3(256), 0, stream, x, mem, pos, Vinb, Pb);
  hipLaunchKernelGGL(k_wtall, dim3(16, 16, 5), dim3(256), 0, stream,
                     Wq, Wk, Wv, Wr, Wo, WqT, WkT, WvT, WrT, WoT);
  hipLaunchKernelGGL(k_proj, dim3(832), dim3(256), 0, stream,
                     Vinb, Pb, WqT, WkT, WvT, WrT, rwb, rrb, qwb, qrb, kb, vb, rkb);
  hipLaunchKernelGGL(k_vt, dim3(2048), dim3(256), 0, stream, vb, vtb);
  hipLaunchKernelGGL(k_attn, dim3(16, 16, 4), dim3(256), 0, stream,
                     qwb, qrb, kb, vtb, rkb, mask, po, pm, pl);
  hipLaunchKernelGGL(k_combine, dim3(2048), dim3(256), 0, stream, po, pm, pl, attnb);
  hipLaunchKernelGGL(k_gemm_out64, dim3(32, 8), dim3(256), 0, stream,
                     attnb, WoT, out);
}

// Round 3
// 268.949 us; speedup vs baseline: 1.1854x; 1.1240x over previous
//
#include <hip/hip_runtime.h>
#include <stdint.h>

#define Bz 2
#define Tq 1024
#define Mm 1024
#define Hh 16
#define Ll 2048
#define Rr 3072

typedef __attribute__((ext_vector_type(8))) short bf16x8;
typedef __attribute__((ext_vector_type(4))) float f32x4;

typedef __attribute__((address_space(3))) uint8_t lds_u8_t;
typedef __attribute__((address_space(1))) uint8_t glb_u8_t;

__device__ __forceinline__ void gl2lds16(const void* g, void* l) {
  __builtin_amdgcn_global_load_lds((const glb_u8_t*)g, (lds_u8_t*)l, 16, 0, 0);
}

__device__ __forceinline__ unsigned short f2bf(float f) {
  unsigned int u = __builtin_bit_cast(unsigned int, f);
  u = u + 0x7fffu + ((u >> 16) & 1u);
  return (unsigned short)(u >> 16);
}
__device__ __forceinline__ float b2f(unsigned short s) {
  unsigned int u = ((unsigned int)s) << 16;
  return __builtin_bit_cast(float, u);
}

// ------- prep: concat+cast values | cast pos | mask -> bf16 additive bias ---
__global__ __launch_bounds__(256) void k_prep(const float* __restrict__ x,
                                              const float* __restrict__ mem,
                                              const float* __restrict__ pos,
                                              const float* __restrict__ mask,
                                              unsigned short* __restrict__ vin,
                                              unsigned short* __restrict__ pb,
                                              unsigned short* __restrict__ mb) {
  int bid = blockIdx.x;
  if (bid < 4096) {
    int idx = bid * 256 + threadIdx.x;
    int e = idx << 2;
    int row = e >> 10, col = e & 1023;
    int b = row >> 11, l = row & 2047;
    const float* s = (l < Mm) ? (mem + (((size_t)b * Mm + l) << 10) + col)
                              : (x + (((size_t)b * Tq + (l - Mm)) << 10) + col);
    float4 v = *(const float4*)s;
    ushort4 o;
    o.x = f2bf(v.x); o.y = f2bf(v.y); o.z = f2bf(v.z); o.w = f2bf(v.w);
    *(ushort4*)(vin + e) = o;
  } else if (bid < 7168) {
    int idx = (bid - 4096) * 256 + threadIdx.x;
    int e = idx << 2;
    float4 v = *(const float4*)(pos + e);
    ushort4 t;
    t.x = f2bf(v.x); t.y = f2bf(v.y); t.z = f2bf(v.z); t.w = f2bf(v.w);
    *(ushort4*)(pb + e) = t;
  } else {
    int idx = (bid - 7168) * 256 + threadIdx.x;
    int e = idx << 2;
    const float BIGM = 1.442695e30f;
    float4 v = *(const float4*)(mask + e);
    ushort4 t;
    t.x = f2bf((1.0f - v.x) * BIGM); t.y = f2bf((1.0f - v.y) * BIGM);
    t.z = f2bf((1.0f - v.z) * BIGM); t.w = f2bf((1.0f - v.w) * BIGM);
    *(ushort4*)(mb + e) = t;
  }
}

// ---------------- prep: transpose-cast 5 weight matrices (1024x1024) --------
__global__ __launch_bounds__(256) void k_wtall(
    const float* __restrict__ w0, const float* __restrict__ w1,
    const float* __restrict__ w2, const float* __restrict__ w3,
    const float* __restrict__ w4,
    unsigned short* __restrict__ t0, unsigned short* __restrict__ t1,
    unsigned short* __restrict__ t2, unsigned short* __restrict__ t3,
    unsigned short* __restrict__ t4) {
  const float* W;
  unsigned short* WT;
  switch (blockIdx.z) {
    case 0: W = w0; WT = t0; break;
    case 1: W = w1; WT = t1; break;
    case 2: W = w2; WT = t2; break;
    case 3: W = w3; WT = t3; break;
    default: W = w4; WT = t4; break;
  }
  __shared__ float tile[64][65];
  int k0 = blockIdx.x * 64, n0 = blockIdx.y * 64;
  int tid = threadIdx.x;
  int rr = tid >> 4, c4 = (tid & 15) * 4;
#pragma unroll
  for (int it = 0; it < 4; ++it) {
    int r = rr + it * 16;
    float4 v = *(const float4*)(W + (size_t)(k0 + r) * 1024 + n0 + c4);
    tile[r][c4] = v.x; tile[r][c4 + 1] = v.y;
    tile[r][c4 + 2] = v.z; tile[r][c4 + 3] = v.w;
  }
  __syncthreads();
#pragma unroll
  for (int it = 0; it < 4; ++it) {
    int n = rr + it * 16;
    ushort4 o;
    o.x = f2bf(tile[c4 + 0][n]); o.y = f2bf(tile[c4 + 1][n]);
    o.z = f2bf(tile[c4 + 2][n]); o.w = f2bf(tile[c4 + 3][n]);
    *(ushort4*)(WT + (size_t)(n0 + n) * 1024 + k0 + c4) = o;
  }
}

// ---------------- bf16 NT GEMM core (m97 structure, K=1024) -----------------
template <int RMAP>
__device__ __forceinline__ void gemm_core(const unsigned short* __restrict__ A,
                                          const unsigned short* __restrict__ Bt,
                                          int m0, int n0, unsigned short* As,
                                          unsigned short* Bs, f32x4 acc[4][4]) {
  const int tid = threadIdx.x;
  const int w = tid >> 6, lane = tid & 63;
  const int quad = lane >> 4, li = lane & 15;
  const int wr = w >> 1, wc = w & 1;
  f32x4 z = {0.f, 0.f, 0.f, 0.f};
#pragma unroll
  for (int mi = 0; mi < 4; ++mi)
#pragma unroll
    for (int ni = 0; ni < 4; ++ni) acc[mi][ni] = z;

  const int rs = lane >> 2;
  const int cs = lane & 3;

  for (int k0 = 0; k0 < 1024; k0 += 32) {
    __syncthreads();
#pragma unroll
    for (int s = 0; s < 2; ++s) {
      int i = w * 2 + s;
      int r = i * 16 + rs;
      int c = cs ^ ((r >> 1) & 3);
      int ar = m0 + r;
      if (RMAP) ar = ar + 1024 + (ar & 1024);
      gl2lds16(A + (size_t)ar * 1024 + k0 + c * 8, (char*)As + i * 1024);
      int br = n0 + r;
      gl2lds16(Bt + (size_t)br * 1024 + k0 + c * 8, (char*)Bs + i * 1024);
    }
    __syncthreads();
    bf16x8 af[4], bfr[4];
#pragma unroll
    for (int mi = 0; mi < 4; ++mi) {
      int r = wr * 64 + mi * 16 + li;
      int ch = quad ^ ((r >> 1) & 3);
      af[mi] = *(const bf16x8*)((const char*)As + r * 64 + ch * 16);
    }
#pragma unroll
    for (int ni = 0; ni < 4; ++ni) {
      int r = wc * 64 + ni * 16 + li;
      int ch = quad ^ ((r >> 1) & 3);
      bfr[ni] = *(const bf16x8*)((const char*)Bs + r * 64 + ch * 16);
    }
#pragma unroll
    for (int mi = 0; mi < 4; ++mi)
#pragma unroll
      for (int ni = 0; ni < 4; ++ni)
        acc[mi][ni] = __builtin_amdgcn_mfma_f32_16x16x32_bf16(
            af[mi], bfr[ni], acc[mi][ni], 0, 0, 0);
  }
}

// fused q (dual-bias) | k | v (direct-transposed out) | rk projections
__global__ __launch_bounds__(256) void k_proj(
    const unsigned short* __restrict__ Vin, const unsigned short* __restrict__ Pb,
    const unsigned short* __restrict__ WqT, const unsigned short* __restrict__ WkT,
    const unsigned short* __restrict__ WvT, const unsigned short* __restrict__ WrT,
    const float* __restrict__ rwb, const float* __restrict__ rrb,
    unsigned short* __restrict__ qwb, unsigned short* __restrict__ qrb,
    unsigned short* __restrict__ kb, unsigned short* __restrict__ vtb,
    unsigned short* __restrict__ rkb) {
  __shared__ unsigned short As[128 * 32];
  __shared__ unsigned short Bs[128 * 32];
  const int t = blockIdx.x;
  const int tid = threadIdx.x, w = tid >> 6, lane = tid & 63;
  const int quad = lane >> 4, li = lane & 15, wr = w >> 1, wc = w & 1;
  f32x4 acc[4][4];

  if (t < 256) {  // k: M=4096, N=1024
    int m0 = (t >> 3) * 128, n0 = (t & 7) * 128;
    gemm_core<0>(Vin, WkT, m0, n0, As, Bs, acc);
#pragma unroll
    for (int mi = 0; mi < 4; ++mi)
#pragma unroll
      for (int ni = 0; ni < 4; ++ni)
#pragma unroll
        for (int reg = 0; reg < 4; ++reg) {
          int rrow = m0 + wr * 64 + mi * 16 + quad * 4 + reg;
          int cc = n0 + wc * 64 + ni * 16 + li;
          kb[(size_t)rrow * 1024 + cc] = f2bf(acc[mi][ni][reg]);
        }
  } else if (t < 512) {  // v: write vtb[b,h,dv,l] directly (ushort4 over l)
    int tt = t - 256;
    int m0 = (tt >> 3) * 128, n0 = (tt & 7) * 128;
    gemm_core<0>(Vin, WvT, m0, n0, As, Bs, acc);
#pragma unroll
    for (int mi = 0; mi < 4; ++mi)
#pragma unroll
      for (int ni = 0; ni < 4; ++ni) {
        int r0 = m0 + wr * 64 + mi * 16 + quad * 4;  // value row, 4-aligned
        int b = r0 >> 11, l0 = r0 & 2047;
        int cc = n0 + wc * 64 + ni * 16 + li;        // h*64+dv
        ushort4 o;
        o.x = f2bf(acc[mi][ni][0]); o.y = f2bf(acc[mi][ni][1]);
        o.z = f2bf(acc[mi][ni][2]); o.w = f2bf(acc[mi][ni][3]);
        *(ushort4*)(vtb + ((size_t)(b * 1024 + cc)) * Ll + l0) = o;
      }
  } else if (t < 640) {  // q dual
    int tt = t - 512;
    int m0 = (tt >> 3) * 128, n0 = (tt & 7) * 128;
    gemm_core<1>(Vin, WqT, m0, n0, As, Bs, acc);
#pragma unroll
    for (int mi = 0; mi < 4; ++mi)
#pragma unroll
      for (int ni = 0; ni < 4; ++ni) {
        int cc = n0 + wc * 64 + ni * 16 + li;
        float bw_ = rwb[cc], br_ = rrb[cc];
#pragma unroll
        for (int reg = 0; reg < 4; ++reg) {
          int rrow = m0 + wr * 64 + mi * 16 + quad * 4 + reg;
          size_t off = (size_t)rrow * 1024 + cc;
          qwb[off] = f2bf(acc[mi][ni][reg] + bw_);
          qrb[off] = f2bf(acc[mi][ni][reg] + br_);
        }
      }
  } else {  // rk: M=3072
    int tt = t - 640;
    int m0 = (tt >> 3) * 128, n0 = (tt & 7) * 128;
    gemm_core<0>(Pb, WrT, m0, n0, As, Bs, acc);
#pragma unroll
    for (int mi = 0; mi < 4; ++mi)
#pragma unroll
      for (int ni = 0; ni < 4; ++ni)
#pragma unroll
        for (int reg = 0; reg < 4; ++reg) {
          int rrow = m0 + wr * 64 + mi * 16 + quad * 4 + reg;
          int cc = n0 + wc * 64 + ni * 16 + li;
          rkb[(size_t)rrow * 1024 + cc] = f2bf(acc[mi][ni][reg]);
        }
  }
}

// output projection, 64x128 tile (256 blocks), fp32 out -> d_out
__global__ __launch_bounds__(256) void k_gemm_out64(
    const unsigned short* __restrict__ attnb, const unsigned short* __restrict__ WoT,
    float* __restrict__ out) {
  __shared__ unsigned short As[64 * 32];
  __shared__ unsigned short Bs[128 * 32];
  int m0 = blockIdx.x * 64, n0 = blockIdx.y * 128;
  const int tid = threadIdx.x, w = tid >> 6, lane = tid & 63;
  const int quad = lane >> 4, li = lane & 15, wr = w >> 1, wc = w & 1;
  f32x4 z = {0.f, 0.f, 0.f, 0.f};
  f32x4 acc[2][4];
#pragma unroll
  for (int mi = 0; mi < 2; ++mi)
#pragma unroll
    for (int ni = 0; ni < 4; ++ni) acc[mi][ni] = z;
  const int rs = lane >> 2, cs = lane & 3;
  for (int k0 = 0; k0 < 1024; k0 += 32) {
    __syncthreads();
    {
      int r = w * 16 + rs;
      int c = cs ^ ((r >> 1) & 3);
      gl2lds16(attnb + (size_t)(m0 + r) * 1024 + k0 + c * 8, (char*)As + w * 1024);
    }
#pragma unroll
    for (int s = 0; s < 2; ++s) {
      int i = w * 2 + s;
      int r = i * 16 + rs;
      int c = cs ^ ((r >> 1) & 3);
      gl2lds16(WoT + (size_t)(n0 + r) * 1024 + k0 + c * 8, (char*)Bs + i * 1024);
    }
    __syncthreads();
    bf16x8 af[2], bfr[4];
#pragma unroll
    for (int mi = 0; mi < 2; ++mi) {
      int r = wr * 32 + mi * 16 + li;
      int ch = quad ^ ((r >> 1) & 3);
      af[mi] = *(const bf16x8*)((const char*)As + r * 64 + ch * 16);
    }
#pragma unroll
    for (int ni = 0; ni < 4; ++ni) {
      int r = wc * 64 + ni * 16 + li;
      int ch = quad ^ ((r >> 1) & 3);
      bfr[ni] = *(const bf16x8*)((const char*)Bs + r * 64 + ch * 16);
    }
#pragma unroll
    for (int mi = 0; mi < 2; ++mi)
#pragma unroll
      for (int ni = 0; ni < 4; ++ni)
        acc[mi][ni] = __builtin_amdgcn_mfma_f32_16x16x32_bf16(
            af[mi], bfr[ni], acc[mi][ni], 0, 0, 0);
  }
#pragma unroll
  for (int mi = 0; mi < 2; ++mi)
#pragma unroll
    for (int ni = 0; ni < 4; ++ni)
#pragma unroll
      for (int reg = 0; reg < 4; ++reg) {
        int rrow = m0 + wr * 32 + mi * 16 + quad * 4 + reg;
        int cc = n0 + wc * 64 + ni * 16 + li;
        out[(size_t)rrow * 1024 + cc] = acc[mi][ni][reg];
      }
}

// ---------------- flash attention, TXL rel-shift, fixed-max softmax ---------
// grid (T/64, H, B*2); wave w owns q rows [qt*64+w*16,+16) x 64 keys/jt.
// No running max: p = exp2(s); l accumulated via ones-fragment MFMA.
// Rs is a 128-row rotating window (64 new rows per jt after preload).
// LDS = 8K + 8K + 16K + 9216 (band/P shared ushort region) = 41984 B.
__global__ __launch_bounds__(256, 3) void k_attn(
    const unsigned short* __restrict__ qw, const unsigned short* __restrict__ qr,
    const unsigned short* __restrict__ kb, const unsigned short* __restrict__ vt,
    const unsigned short* __restrict__ rkb, const unsigned short* __restrict__ mb,
    float* __restrict__ po, float* __restrict__ pl) {
  __shared__ unsigned short Ks[64 * 64];
  __shared__ unsigned short Vs[64 * 64];
  __shared__ unsigned short Rs[128 * 64];
  __shared__ unsigned short BndP[4][16 * 72];  // band then P, per wave

  const int tid = threadIdx.x;
  const int w = tid >> 6, lane = tid & 63;
  const int quad = lane >> 4, li = lane & 15;
  const int qt = blockIdx.x, h = blockIdx.y;
  const int b = blockIdx.z >> 1, split = blockIdx.z & 1;
  const int t0blk = qt * 64;
  const int t0w = t0blk + w * 16;
  const int rboff = 48 - 16 * w;
  const int rbase0 = Tq - t0blk - 63 + (split << 10);

  bf16x8 aqw[2], aqr[2];
  {
    const unsigned short* p1 = qw + ((size_t)((b * Tq + t0w + li) * Hh + h)) * 64;
    aqw[0] = *(const bf16x8*)(p1 + quad * 8);
    aqw[1] = *(const bf16x8*)(p1 + 32 + quad * 8);
    const unsigned short* p2 = qr + ((size_t)((b * Tq + t0w + li) * Hh + h)) * 64;
    aqr[0] = *(const bf16x8*)(p2 + quad * 8);
    aqr[1] = *(const bf16x8*)(p2 + 32 + quad * 8);
  }

  f32x4 z = {0.f, 0.f, 0.f, 0.f};
  f32x4 o[4];
  o[0] = z; o[1] = z; o[2] = z; o[3] = z;
  f32x4 ol = z;  // row-sum accumulator (ones-MFMA)

  const int srow = lane >> 3;
  const int scs = lane & 7;
  const float SC = 0.125f * 1.4426950408889634f;
  const short oneb = 0x3F80;
  const bf16x8 onesf = {oneb, oneb, oneb, oneb, oneb, oneb, oneb, oneb};

  unsigned short* pw = &BndP[w][0];

  for (int jt = 0; jt < 16; ++jt) {
    const int j0 = (split << 10) + jt * 64;
    __syncthreads();
#pragma unroll
    for (int s = 0; s < 2; ++s) {
      int i = w * 2 + s;
      int r = i * 8 + srow;
      int c = scs ^ (r & 7);
      gl2lds16(kb + ((size_t)((b * Ll + j0 + r) * Hh + h)) * 64 + c * 8,
               (char*)Ks + i * 1024);
      gl2lds16(vt + ((size_t)((b * Hh + h) * 64 + r)) * Ll + j0 + c * 8,
               (char*)Vs + i * 1024);
    }
    if (jt == 0) {  // preload full 128-row window
#pragma unroll
      for (int s = 0; s < 4; ++s) {
        int i = w * 4 + s;
        int r = i * 8 + srow;
        int gr = rbase0 + r;
        if (gr > Rr - 1) gr = Rr - 1;
        int c = scs ^ (r & 7);
        gl2lds16(rkb + ((size_t)gr * Hh + h) * 64 + c * 8, (char*)Rs + i * 1024);
      }
    } else {  // rotate: load 64 new rows into half ((jt+1)&1)
      int ph0 = (64 * (jt + 1)) & 127;
#pragma unroll
      for (int s = 0; s < 2; ++s) {
        int i2 = w * 2 + s;
        int rr = i2 * 8 + srow;
        int gr = rbase0 + 64 * jt + 64 + rr;
        if (gr > Rr - 1) gr = Rr - 1;
        int c = scs ^ (rr & 7);
        gl2lds16(rkb + ((size_t)gr * Hh + h) * 64 + c * 8,
                 (char*)Rs + ph0 * 128 + i2 * 1024);
      }
    }
    __syncthreads();

    // content scores
    f32x4 sc[4];
    sc[0] = z; sc[1] = z; sc[2] = z; sc[3] = z;
#pragma unroll
    for (int ks = 0; ks < 2; ++ks)
#pragma unroll
      for (int nt = 0; nt < 4; ++nt) {
        int j = nt * 16 + li;
        int ch = (ks * 4 + quad) ^ (j & 7);
        bf16x8 kf = *(const bf16x8*)((const char*)Ks + j * 128 + ch * 16);
        sc[nt] = __builtin_amdgcn_mfma_f32_16x16x32_bf16(aqw[ks], kf, sc[nt], 0, 0, 0);
      }
    // band scores (window rows via rotation)
    f32x4 bd[5];
    bd[0] = z; bd[1] = z; bd[2] = z; bd[3] = z; bd[4] = z;
#pragma unroll
    for (int ks = 0; ks < 2; ++ks)
#pragma unroll
      for (int nt = 0; nt < 5; ++nt) {
        int pr = (rboff + nt * 16 + li + 64 * jt) & 127;
        int ch = (ks * 4 + quad) ^ (pr & 7);
        bf16x8 rf = *(const bf16x8*)((const char*)Rs + pr * 128 + ch * 16);
        bd[nt] = __builtin_amdgcn_mfma_f32_16x16x32_bf16(aqr[ks], rf, bd[nt], 0, 0, 0);
      }
    // shifted band write: element (row, c=nt*16+li) -> key col jj = c+row-15
#pragma unroll
    for (int nt = 0; nt < 5; ++nt)
#pragma unroll
      for (int reg = 0; reg < 4; ++reg) {
        int row = quad * 4 + reg;
        int jj = nt * 16 + li + row - 15;
        if ((unsigned)jj < 64u) pw[row * 72 + jj] = f2bf(bd[nt][reg]);
      }
    __builtin_amdgcn_s_waitcnt(0xc07f);

    // s -> p = exp2(s), write P (same region, after all band reads)
    float pbuf[4][4];
    const unsigned short* mrow0 = mb + ((size_t)(b * Tq + t0w)) * Ll + j0;
#pragma unroll
    for (int nt = 0; nt < 4; ++nt)
#pragma unroll
      for (int reg = 0; reg < 4; ++reg) {
        int row = quad * 4 + reg;
        float rel = b2f(pw[row * 72 + nt * 16 + li]);
        float mv = b2f(mrow0[(size_t)row * Ll + nt * 16 + li]);
        float s = (sc[nt][reg] + rel) * SC - mv;
        pbuf[nt][reg] = exp2f(s);
      }
    asm volatile("" ::: "memory");
#pragma unroll
    for (int nt = 0; nt < 4; ++nt)
#pragma unroll
      for (int reg = 0; reg < 4; ++reg)
        pw[(quad * 4 + reg) * 72 + nt * 16 + li] = f2bf(pbuf[nt][reg]);
    __builtin_amdgcn_s_waitcnt(0xc07f);
    // PV + ones-column row sums
#pragma unroll
    for (int ks = 0; ks < 2; ++ks) {
      bf16x8 ap = *(const bf16x8*)(pw + li * 72 + ks * 32 + quad * 8);
      ol = __builtin_amdgcn_mfma_f32_16x16x32_bf16(ap, onesf, ol, 0, 0, 0);
#pragma unroll
      for (int nt = 0; nt < 4; ++nt) {
        int dv = nt * 16 + li;
        int ch = (ks * 4 + quad) ^ (dv & 7);
        bf16x8 vf = *(const bf16x8*)((const char*)Vs + dv * 128 + ch * 16);
        o[nt] = __builtin_amdgcn_mfma_f32_16x16x32_bf16(ap, vf, o[nt], 0, 0, 0);
      }
    }
  }
  // epilogue: unnormalized partials + row sums
  const int bs = (b * 2 + split) * 16 + h;
#pragma unroll
  for (int nt = 0; nt < 4; ++nt)
#pragma unroll
    for (int reg = 0; reg < 4; ++reg) {
      int trow = t0w + quad * 4 + reg;
      po[((size_t)bs * 1024 + trow) * 64 + nt * 16 + li] = o[nt][reg];
    }
  if (li == 0) {
#pragma unroll
    for (int reg = 0; reg < 4; ++reg) {
      int trow = t0w + quad * 4 + reg;
      pl[(size_t)bs * 1024 + trow] = ol[reg];
    }
  }
}

// ---------------- combine the two kv-split halves -> attnb (bf16) -----------
__global__ __launch_bounds__(256) void k_combine(
    const float* __restrict__ po, const float* __restrict__ pl,
    unsigned short* __restrict__ attnb) {
  int id = blockIdx.x * 256 + threadIdx.x;
  int dv4 = (id & 15) << 2;
  int t = (id >> 4) & 1023;
  int h = (id >> 14) & 15;
  int b = id >> 18;
  size_t r0 = ((size_t)((b * 2 + 0) * 16 + h)) * 1024 + t;
  size_t r1 = ((size_t)((b * 2 + 1) * 16 + h)) * 1024 + t;
  float inv = 1.0f / (pl[r0] + pl[r1]);
  float4 o0 = *(const float4*)(po + r0 * 64 + dv4);
  float4 o1 = *(const float4*)(po + r1 * 64 + dv4);
  ushort4 res;
  res.x = f2bf((o0.x + o1.x) * inv);
  res.y = f2bf((o0.y + o1.y) * inv);
  res.z = f2bf((o0.z + o1.z) * inv);
  res.w = f2bf((o0.w + o1.w) * inv);
  *(ushort4*)(attnb + ((size_t)(b * 1024 + t)) * 1024 + h * 64 + dv4) = res;
}

extern "C" void kernel_launch(void* const* d_in, const int* in_sizes, int n_in,
                              void* d_out, int out_size, void* d_ws, size_t ws_size,
                              hipStream_t stream) {
  const float* x = (const float*)d_in[0];
  const float* mask = (const float*)d_in[1];
  const float* pos = (const float*)d_in[2];
  const float* mem = (const float*)d_in[3];
  const float* Wq = (const float*)d_in[4];
  const float* Wk = (const float*)d_in[5];
  const float* Wv = (const float*)d_in[6];
  const float* Wr = (const float*)d_in[7];
  const float* rwb = (const float*)d_in[8];
  const float* rrb = (const float*)d_in[9];
  const float* Wo = (const float*)d_in[10];
  float* out = (float*)d_out;

  uint8_t* ws = (uint8_t*)d_ws;
  const size_t MB = 1024 * 1024;
  unsigned short* Vinb = (unsigned short*)(ws + 0);        // 8 MB (dead post-proj)
  unsigned short* WqT = (unsigned short*)(ws + 8 * MB);    // dead post-proj
  unsigned short* WkT = (unsigned short*)(ws + 10 * MB);
  unsigned short* WvT = (unsigned short*)(ws + 12 * MB);
  unsigned short* WrT = (unsigned short*)(ws + 14 * MB);
  unsigned short* WoT = (unsigned short*)(ws + 16 * MB);   // live to end
  unsigned short* Pb = (unsigned short*)(ws + 18 * MB);    // dead post-proj
  unsigned short* qwb = (unsigned short*)(ws + 24 * MB);
  unsigned short* qrb = (unsigned short*)(ws + 28 * MB);
  unsigned short* kb = (unsigned short*)(ws + 32 * MB);
  unsigned short* vtb = (unsigned short*)(ws + 40 * MB);   // [B][H][64][2048]
  unsigned short* rkb = (unsigned short*)(ws + 48 * MB);   // 6 MB
  unsigned short* mbb = (unsigned short*)(ws + 54 * MB);   // 8 MB mask bias bf16
  // overlays (live only after the regions below are dead):
  float* po = (float*)(ws + 0);                            // 16 MB (Vinb..WrT dead)
  float* pl = (float*)(ws + 18 * MB);                      // 256 KB (Pb dead)
  unsigned short* attnb = (unsigned short*)(ws + 19 * MB); // 4 MB (in Pb region)

  hipLaunchKernelGGL(k_prep, dim3(11264), dim3(256), 0, stream,
                     x, mem, pos, mask, Vinb, Pb, mbb);
  hipLaunchKernelGGL(k_wtall, dim3(16, 16, 5), dim3(256), 0, stream,
                     Wq, Wk, Wv, Wr, Wo, WqT, WkT, WvT, WrT, WoT);
  hipLaunchKernelGGL(k_proj, dim3(832), dim3(256), 0, stream,
                     Vinb, Pb, WqT, WkT, WvT, WrT, rwb, rrb, qwb, qrb, kb, vtb, rkb);
  hipLaunchKernelGGL(k_attn, dim3(16, 16, 4), dim3(256), 0, stream,
                     qwb, qrb, kb, vtb, rkb, mbb, po, pl);
  hipLaunchKernelGGL(k_combine, dim3(2048), dim3(256), 0, stream, po, pl, attnb);
  hipLaunchKernelGGL(k_gemm_out64, dim3(32, 8), dim3(256), 0, stream,
                     attnb, WoT, out);
}

// Round 5
// 268.826 us; speedup vs baseline: 1.1859x; 1.0005x over previous
//
#include <hip/hip_runtime.h>
#include <hip/hip_fp16.h>
#include <stdint.h>

#define Bz 2
#define Tq 1024
#define Mm 1024
#define Hh 16
#define Ll 2048
#define Rr 3072

typedef __attribute__((ext_vector_type(8))) short bf16x8;
typedef __attribute__((ext_vector_type(4))) float f32x4;

typedef __attribute__((address_space(3))) uint8_t lds_u8_t;
typedef __attribute__((address_space(1))) uint8_t glb_u8_t;

__device__ __forceinline__ void gl2lds16(const void* g, void* l) {
  __builtin_amdgcn_global_load_lds((const glb_u8_t*)g, (lds_u8_t*)l, 16, 0, 0);
}

__device__ __forceinline__ unsigned short f2bf(float f) {
  unsigned int u = __builtin_bit_cast(unsigned int, f);
  u = u + 0x7fffu + ((u >> 16) & 1u);
  return (unsigned short)(u >> 16);
}
__device__ __forceinline__ float b2f(unsigned short s) {
  unsigned int u = ((unsigned int)s) << 16;
  return __builtin_bit_cast(float, u);
}

// ------- prep: concat+cast values | cast pos | mask -> bf16 additive bias ---
// mask is [B,T,M+T] = 2*1024*2048 = 4,194,304 elems -> exactly 4096 blocks.
// (R4 crashed by using 6144 mask blocks: 8 MB OOB read. Keep 11264 total.)
__global__ __launch_bounds__(256) void k_prep(const float* __restrict__ x,
                                              const float* __restrict__ mem,
                                              const float* __restrict__ pos,
                                              const float* __restrict__ mask,
                                              unsigned short* __restrict__ vin,
                                              unsigned short* __restrict__ pb,
                                              unsigned short* __restrict__ mb) {
  int bid = blockIdx.x;
  if (bid < 4096) {
    int idx = bid * 256 + threadIdx.x;
    int e = idx << 2;
    int row = e >> 10, col = e & 1023;
    int b = row >> 11, l = row & 2047;
    const float* s = (l < Mm) ? (mem + (((size_t)b * Mm + l) << 10) + col)
                              : (x + (((size_t)b * Tq + (l - Mm)) << 10) + col);
    float4 v = *(const float4*)s;
    ushort4 o;
    o.x = f2bf(v.x); o.y = f2bf(v.y); o.z = f2bf(v.z); o.w = f2bf(v.w);
    *(ushort4*)(vin + e) = o;
  } else if (bid < 7168) {
    int idx = (bid - 4096) * 256 + threadIdx.x;
    int e = idx << 2;
    float4 v = *(const float4*)(pos + e);
    ushort4 t;
    t.x = f2bf(v.x); t.y = f2bf(v.y); t.z = f2bf(v.z); t.w = f2bf(v.w);
    *(ushort4*)(pb + e) = t;
  } else {
    int idx = (bid - 7168) * 256 + threadIdx.x;
    int e = idx << 2;
    const float BIGM = 1.442695e30f;
    float4 v = *(const float4*)(mask + e);
    ushort4 t;
    t.x = f2bf((1.0f - v.x) * BIGM); t.y = f2bf((1.0f - v.y) * BIGM);
    t.z = f2bf((1.0f - v.z) * BIGM); t.w = f2bf((1.0f - v.w) * BIGM);
    *(ushort4*)(mb + e) = t;
  }
}

// ---------------- prep: transpose-cast 5 weight matrices (1024x1024) --------
__global__ __launch_bounds__(256) void k_wtall(
    const float* __restrict__ w0, const float* __restrict__ w1,
    const float* __restrict__ w2, const float* __restrict__ w3,
    const float* __restrict__ w4,
    unsigned short* __restrict__ t0, unsigned short* __restrict__ t1,
    unsigned short* __restrict__ t2, unsigned short* __restrict__ t3,
    unsigned short* __restrict__ t4) {
  const float* W;
  unsigned short* WT;
  switch (blockIdx.z) {
    case 0: W = w0; WT = t0; break;
    case 1: W = w1; WT = t1; break;
    case 2: W = w2; WT = t2; break;
    case 3: W = w3; WT = t3; break;
    default: W = w4; WT = t4; break;
  }
  __shared__ float tile[64][65];
  int k0 = blockIdx.x * 64, n0 = blockIdx.y * 64;
  int tid = threadIdx.x;
  int rr = tid >> 4, c4 = (tid & 15) * 4;
#pragma unroll
  for (int it = 0; it < 4; ++it) {
    int r = rr + it * 16;
    float4 v = *(const float4*)(W + (size_t)(k0 + r) * 1024 + n0 + c4);
    tile[r][c4] = v.x; tile[r][c4 + 1] = v.y;
    tile[r][c4 + 2] = v.z; tile[r][c4 + 3] = v.w;
  }
  __syncthreads();
#pragma unroll
  for (int it = 0; it < 4; ++it) {
    int n = rr + it * 16;
    ushort4 o;
    o.x = f2bf(tile[c4 + 0][n]); o.y = f2bf(tile[c4 + 1][n]);
    o.z = f2bf(tile[c4 + 2][n]); o.w = f2bf(tile[c4 + 3][n]);
    *(ushort4*)(WT + (size_t)(n0 + n) * 1024 + k0 + c4) = o;
  }
}

// ---------------- bf16 NT GEMM core (m97 structure, K=1024) -----------------
template <int RMAP>
__device__ __forceinline__ void gemm_core(const unsigned short* __restrict__ A,
                                          const unsigned short* __restrict__ Bt,
                                          int m0, int n0, unsigned short* As,
                                          unsigned short* Bs, f32x4 acc[4][4]) {
  const int tid = threadIdx.x;
  const int w = tid >> 6, lane = tid & 63;
  const int quad = lane >> 4, li = lane & 15;
  const int wr = w >> 1, wc = w & 1;
  f32x4 z = {0.f, 0.f, 0.f, 0.f};
#pragma unroll
  for (int mi = 0; mi < 4; ++mi)
#pragma unroll
    for (int ni = 0; ni < 4; ++ni) acc[mi][ni] = z;

  const int rs = lane >> 2;
  const int cs = lane & 3;

  for (int k0 = 0; k0 < 1024; k0 += 32) {
    __syncthreads();
#pragma unroll
    for (int s = 0; s < 2; ++s) {
      int i = w * 2 + s;
      int r = i * 16 + rs;
      int c = cs ^ ((r >> 1) & 3);
      int ar = m0 + r;
      if (RMAP) ar = ar + 1024 + (ar & 1024);
      gl2lds16(A + (size_t)ar * 1024 + k0 + c * 8, (char*)As + i * 1024);
      int br = n0 + r;
      gl2lds16(Bt + (size_t)br * 1024 + k0 + c * 8, (char*)Bs + i * 1024);
    }
    __syncthreads();
    bf16x8 af[4], bfr[4];
#pragma unroll
    for (int mi = 0; mi < 4; ++mi) {
      int r = wr * 64 + mi * 16 + li;
      int ch = quad ^ ((r >> 1) & 3);
      af[mi] = *(const bf16x8*)((const char*)As + r * 64 + ch * 16);
    }
#pragma unroll
    for (int ni = 0; ni < 4; ++ni) {
      int r = wc * 64 + ni * 16 + li;
      int ch = quad ^ ((r >> 1) & 3);
      bfr[ni] = *(const bf16x8*)((const char*)Bs + r * 64 + ch * 16);
    }
#pragma unroll
    for (int mi = 0; mi < 4; ++mi)
#pragma unroll
      for (int ni = 0; ni < 4; ++ni)
        acc[mi][ni] = __builtin_amdgcn_mfma_f32_16x16x32_bf16(
            af[mi], bfr[ni], acc[mi][ni], 0, 0, 0);
  }
}

// fused q (dual-bias) | k | v (direct-transposed out) | rk projections
__global__ __launch_bounds__(256) void k_proj(
    const unsigned short* __restrict__ Vin, const unsigned short* __restrict__ Pb,
    const unsigned short* __restrict__ WqT, const unsigned short* __restrict__ WkT,
    const unsigned short* __restrict__ WvT, const unsigned short* __restrict__ WrT,
    const float* __restrict__ rwb, const float* __restrict__ rrb,
    unsigned short* __restrict__ qwb, unsigned short* __restrict__ qrb,
    unsigned short* __restrict__ kb, unsigned short* __restrict__ vtb,
    unsigned short* __restrict__ rkb) {
  __shared__ unsigned short As[128 * 32];
  __shared__ unsigned short Bs[128 * 32];
  const int t = blockIdx.x;
  const int tid = threadIdx.x, w = tid >> 6, lane = tid & 63;
  const int quad = lane >> 4, li = lane & 15, wr = w >> 1, wc = w & 1;
  f32x4 acc[4][4];

  if (t < 256) {  // k: M=4096, N=1024
    int m0 = (t >> 3) * 128, n0 = (t & 7) * 128;
    gemm_core<0>(Vin, WkT, m0, n0, As, Bs, acc);
#pragma unroll
    for (int mi = 0; mi < 4; ++mi)
#pragma unroll
      for (int ni = 0; ni < 4; ++ni)
#pragma unroll
        for (int reg = 0; reg < 4; ++reg) {
          int rrow = m0 + wr * 64 + mi * 16 + quad * 4 + reg;
          int cc = n0 + wc * 64 + ni * 16 + li;
          kb[(size_t)rrow * 1024 + cc] = f2bf(acc[mi][ni][reg]);
        }
  } else if (t < 512) {  // v: write vtb[b,h,dv,l] directly (ushort4 over l)
    int tt = t - 256;
    int m0 = (tt >> 3) * 128, n0 = (tt & 7) * 128;
    gemm_core<0>(Vin, WvT, m0, n0, As, Bs, acc);
#pragma unroll
    for (int mi = 0; mi < 4; ++mi)
#pragma unroll
      for (int ni = 0; ni < 4; ++ni) {
        int r0 = m0 + wr * 64 + mi * 16 + quad * 4;  // value row, 4-aligned
        int b = r0 >> 11, l0 = r0 & 2047;
        int cc = n0 + wc * 64 + ni * 16 + li;        // h*64+dv
        ushort4 o;
        o.x = f2bf(acc[mi][ni][0]); o.y = f2bf(acc[mi][ni][1]);
        o.z = f2bf(acc[mi][ni][2]); o.w = f2bf(acc[mi][ni][3]);
        *(ushort4*)(vtb + ((size_t)(b * 1024 + cc)) * Ll + l0) = o;
      }
  } else if (t < 640) {  // q dual
    int tt = t - 512;
    int m0 = (tt >> 3) * 128, n0 = (tt & 7) * 128;
    gemm_core<1>(Vin, WqT, m0, n0, As, Bs, acc);
#pragma unroll
    for (int mi = 0; mi < 4; ++mi)
#pragma unroll
      for (int ni = 0; ni < 4; ++ni) {
        int cc = n0 + wc * 64 + ni * 16 + li;
        float bw_ = rwb[cc], br_ = rrb[cc];
#pragma unroll
        for (int reg = 0; reg < 4; ++reg) {
          int rrow = m0 + wr * 64 + mi * 16 + quad * 4 + reg;
          size_t off = (size_t)rrow * 1024 + cc;
          qwb[off] = f2bf(acc[mi][ni][reg] + bw_);
          qrb[off] = f2bf(acc[mi][ni][reg] + br_);
        }
      }
  } else {  // rk: M=3072
    int tt = t - 640;
    int m0 = (tt >> 3) * 128, n0 = (tt & 7) * 128;
    gemm_core<0>(Pb, WrT, m0, n0, As, Bs, acc);
#pragma unroll
    for (int mi = 0; mi < 4; ++mi)
#pragma unroll
      for (int ni = 0; ni < 4; ++ni)
#pragma unroll
        for (int reg = 0; reg < 4; ++reg) {
          int rrow = m0 + wr * 64 + mi * 16 + quad * 4 + reg;
          int cc = n0 + wc * 64 + ni * 16 + li;
          rkb[(size_t)rrow * 1024 + cc] = f2bf(acc[mi][ni][reg]);
        }
  }
}

// output projection, 64x128 tile (256 blocks), fp32 out -> d_out
__global__ __launch_bounds__(256) void k_gemm_out64(
    const unsigned short* __restrict__ attnb, const unsigned short* __restrict__ WoT,
    float* __restrict__ out) {
  __shared__ unsigned short As[64 * 32];
  __shared__ unsigned short Bs[128 * 32];
  int m0 = blockIdx.x * 64, n0 = blockIdx.y * 128;
  const int tid = threadIdx.x, w = tid >> 6, lane = tid & 63;
  const int quad = lane >> 4, li = lane & 15, wr = w >> 1, wc = w & 1;
  f32x4 z = {0.f, 0.f, 0.f, 0.f};
  f32x4 acc[2][4];
#pragma unroll
  for (int mi = 0; mi < 2; ++mi)
#pragma unroll
    for (int ni = 0; ni < 4; ++ni) acc[mi][ni] = z;
  const int rs = lane >> 2, cs = lane & 3;
  for (int k0 = 0; k0 < 1024; k0 += 32) {
    __syncthreads();
    {
      int r = w * 16 + rs;
      int c = cs ^ ((r >> 1) & 3);
      gl2lds16(attnb + (size_t)(m0 + r) * 1024 + k0 + c * 8, (char*)As + w * 1024);
    }
#pragma unroll
    for (int s = 0; s < 2; ++s) {
      int i = w * 2 + s;
      int r = i * 16 + rs;
      int c = cs ^ ((r >> 1) & 3);
      gl2lds16(WoT + (size_t)(n0 + r) * 1024 + k0 + c * 8, (char*)Bs + i * 1024);
    }
    __syncthreads();
    bf16x8 af[2], bfr[4];
#pragma unroll
    for (int mi = 0; mi < 2; ++mi) {
      int r = wr * 32 + mi * 16 + li;
      int ch = quad ^ ((r >> 1) & 3);
      af[mi] = *(const bf16x8*)((const char*)As + r * 64 + ch * 16);
    }
#pragma unroll
    for (int ni = 0; ni < 4; ++ni) {
      int r = wc * 64 + ni * 16 + li;
      int ch = quad ^ ((r >> 1) & 3);
      bfr[ni] = *(const bf16x8*)((const char*)Bs + r * 64 + ch * 16);
    }
#pragma unroll
    for (int mi = 0; mi < 2; ++mi)
#pragma unroll
      for (int ni = 0; ni < 4; ++ni)
        acc[mi][ni] = __builtin_amdgcn_mfma_f32_16x16x32_bf16(
            af[mi], bfr[ni], acc[mi][ni], 0, 0, 0);
  }
#pragma unroll
  for (int mi = 0; mi < 2; ++mi)
#pragma unroll
    for (int ni = 0; ni < 4; ++ni)
#pragma unroll
      for (int reg = 0; reg < 4; ++reg) {
        int rrow = m0 + wr * 32 + mi * 16 + quad * 4 + reg;
        int cc = n0 + wc * 64 + ni * 16 + li;
        out[(size_t)rrow * 1024 + cc] = acc[mi][ni][reg];
      }
}

// ---------------- flash attention, TXL rel-shift, register-shift softmax ----
// grid (T/64, H, B*2); wave w owns q rows [qt*64+w*16,+16) x 64 keys/jt.
// sc is rotated in-register (shfl) to align with band C-layout; s=sc_rot+bd
// written once to LDS (f16, shifted slot = key col); read back in A-layout
// (2xb64/ks), scale+mask+exp2 in A-layout, PV MFMA fed from VGPRs (no P
// round-trip). l via ones-MFMA. LDS = 8K+8K+16K+9216 = 41984 B, 3 blocks/CU.
__global__ __launch_bounds__(256, 3) void k_attn(
    const unsigned short* __restrict__ qw, const unsigned short* __restrict__ qr,
    const unsigned short* __restrict__ kb, const unsigned short* __restrict__ vt,
    const unsigned short* __restrict__ rkb, const unsigned short* __restrict__ mb,
    float* __restrict__ po, float* __restrict__ pl) {
  __shared__ unsigned short Ks[64 * 64];
  __shared__ unsigned short Vs[64 * 64];
  __shared__ unsigned short Rs[128 * 64];
  __shared__ unsigned short Sb[4][16 * 72];  // per-wave s (f16), [row][key]

  const int tid = threadIdx.x;
  const int w = tid >> 6, lane = tid & 63;
  const int quad = lane >> 4, li = lane & 15;
  const int qt = blockIdx.x, h = blockIdx.y;
  const int b = blockIdx.z >> 1, split = blockIdx.z & 1;
  const int t0blk = qt * 64;
  const int t0w = t0blk + w * 16;
  const int rboff = 48 - 16 * w;
  const int rbase0 = Tq - t0blk - 63 + (split << 10);

  bf16x8 aqw[2], aqr[2];
  {
    const unsigned short* p1 = qw + ((size_t)((b * Tq + t0w + li) * Hh + h)) * 64;
    aqw[0] = *(const bf16x8*)(p1 + quad * 8);
    aqw[1] = *(const bf16x8*)(p1 + 32 + quad * 8);
    const unsigned short* p2 = qr + ((size_t)((b * Tq + t0w + li) * Hh + h)) * 64;
    aqr[0] = *(const bf16x8*)(p2 + quad * 8);
    aqr[1] = *(const bf16x8*)(p2 + 32 + quad * 8);
  }

  f32x4 z = {0.f, 0.f, 0.f, 0.f};
  f32x4 o[4];
  o[0] = z; o[1] = z; o[2] = z; o[3] = z;
  f32x4 ol = z;  // row-sum accumulator (ones-MFMA)

  const int srow = lane >> 3;
  const int scs = lane & 7;
  const float SC = 0.125f * 1.4426950408889634f;
  const short oneb = 0x3F80;
  const bf16x8 onesf = {oneb, oneb, oneb, oneb, oneb, oneb, oneb, oneb};

  unsigned short* pw = &Sb[w][0];
  // A-layout mask row pointer: lane li holds t-row = t0w + li
  const unsigned short* mrowA = mb + ((size_t)(b * Tq + t0w + li)) * Ll;
  // shfl source lanes per reg (rotation by (row-15) mod 16 within 16-group)
  int srcl[4];
#pragma unroll
  for (int reg = 0; reg < 4; ++reg) {
    int row = quad * 4 + reg;
    srcl[reg] = (lane & 48) + ((li + row + 1) & 15);
  }

  for (int jt = 0; jt < 16; ++jt) {
    const int j0 = (split << 10) + jt * 64;
    __syncthreads();
#pragma unroll
    for (int s = 0; s < 2; ++s) {
      int i = w * 2 + s;
      int r = i * 8 + srow;
      int c = scs ^ (r & 7);
      gl2lds16(kb + ((size_t)((b * Ll + j0 + r) * Hh + h)) * 64 + c * 8,
               (char*)Ks + i * 1024);
      gl2lds16(vt + ((size_t)((b * Hh + h) * 64 + r)) * Ll + j0 + c * 8,
               (char*)Vs + i * 1024);
    }
    if (jt == 0) {  // preload full 128-row window
#pragma unroll
      for (int s = 0; s < 4; ++s) {
        int i = w * 4 + s;
        int r = i * 8 + srow;
        int gr = rbase0 + r;
        if (gr > Rr - 1) gr = Rr - 1;
        int c = scs ^ (r & 7);
        gl2lds16(rkb + ((size_t)gr * Hh + h) * 64 + c * 8, (char*)Rs + i * 1024);
      }
    } else {  // rotate: load 64 new rows
      int ph0 = (64 * (jt + 1)) & 127;
#pragma unroll
      for (int s = 0; s < 2; ++s) {
        int i2 = w * 2 + s;
        int rr = i2 * 8 + srow;
        int gr = rbase0 + 64 * jt + 64 + rr;
        if (gr > Rr - 1) gr = Rr - 1;
        int c = scs ^ (rr & 7);
        gl2lds16(rkb + ((size_t)gr * Hh + h) * 64 + c * 8,
                 (char*)Rs + ph0 * 128 + i2 * 1024);
      }
    }
    __syncthreads();

    // content scores (C-layout)
    f32x4 sc[4];
    sc[0] = z; sc[1] = z; sc[2] = z; sc[3] = z;
#pragma unroll
    for (int ks = 0; ks < 2; ++ks)
#pragma unroll
      for (int nt = 0; nt < 4; ++nt) {
        int j = nt * 16 + li;
        int ch = (ks * 4 + quad) ^ (j & 7);
        bf16x8 kf = *(const bf16x8*)((const char*)Ks + j * 128 + ch * 16);
        sc[nt] = __builtin_amdgcn_mfma_f32_16x16x32_bf16(aqw[ks], kf, sc[nt], 0, 0, 0);
      }
    // band scores (window rows via rotation)
    f32x4 bd[5];
    bd[0] = z; bd[1] = z; bd[2] = z; bd[3] = z; bd[4] = z;
#pragma unroll
    for (int ks = 0; ks < 2; ++ks)
#pragma unroll
      for (int nt = 0; nt < 5; ++nt) {
        int pr = (rboff + nt * 16 + li + 64 * jt) & 127;
        int ch = (ks * 4 + quad) ^ (pr & 7);
        bf16x8 rf = *(const bf16x8*)((const char*)Rs + pr * 128 + ch * 16);
        bd[nt] = __builtin_amdgcn_mfma_f32_16x16x32_bf16(aqr[ks], rf, bd[nt], 0, 0, 0);
      }
    // rotate sc into band column space: rot[nt][reg] = sc row `row`,
    // col nt*16 + ((li+row-15)&15)
    float rot[4][4];
#pragma unroll
    for (int nt = 0; nt < 4; ++nt)
#pragma unroll
      for (int reg = 0; reg < 4; ++reg)
        rot[nt][reg] = __shfl(sc[nt][reg], srcl[reg], 64);
    // s = sc(aligned) + bd, store f16 at shifted slot (row, jj)
#pragma unroll
    for (int nt = 0; nt < 5; ++nt)
#pragma unroll
      for (int reg = 0; reg < 4; ++reg) {
        int row = quad * 4 + reg;
        int jj = nt * 16 + li + row - 15;
        int ntlo = (nt == 0) ? 3 : (nt - 1);
        int nthi = (nt > 3) ? 0 : nt;
        float val = ((li + row) >= 15) ? rot[nthi][reg] : rot[ntlo][reg];
        float s = val + bd[nt][reg];
        if ((unsigned)jj < 64u)
          pw[row * 72 + jj] = __builtin_bit_cast(unsigned short, __float2half(s));
      }
    __builtin_amdgcn_s_waitcnt(0xc07f);

    // A-layout: read s (lane li = t-row li, keys cofs..cofs+7), mask b128,
    // exp2, feed PV MFMA directly from registers
#pragma unroll
    for (int ks = 0; ks < 2; ++ks) {
      const int cofs = ks * 32 + quad * 8;
      ushort4 s0 = *(const ushort4*)(pw + li * 72 + cofs);
      ushort4 s1 = *(const ushort4*)(pw + li * 72 + cofs + 4);
      bf16x8 mv = *(const bf16x8*)(mrowA + j0 + cofs);
      unsigned short su[8] = {s0.x, s0.y, s0.z, s0.w, s1.x, s1.y, s1.z, s1.w};
      bf16x8 ap;
#pragma unroll
      for (int i2 = 0; i2 < 8; ++i2) {
        float sf = __half2float(__builtin_bit_cast(__half, su[i2]));
        float mvf = b2f((unsigned short)mv[i2]);
        float p = exp2f(sf * SC - mvf);
        ap[i2] = (short)f2bf(p);
      }
      ol = __builtin_amdgcn_mfma_f32_16x16x32_bf16(ap, onesf, ol, 0, 0, 0);
#pragma unroll
      for (int nt = 0; nt < 4; ++nt) {
        int dv = nt * 16 + li;
        int ch = (ks * 4 + quad) ^ (dv & 7);
        bf16x8 vf = *(const bf16x8*)((const char*)Vs + dv * 128 + ch * 16);
        o[nt] = __builtin_amdgcn_mfma_f32_16x16x32_bf16(ap, vf, o[nt], 0, 0, 0);
      }
    }
  }
  // epilogue: unnormalized partials + row sums
  const int bs = (b * 2 + split) * 16 + h;
#pragma unroll
  for (int nt = 0; nt < 4; ++nt)
#pragma unroll
    for (int reg = 0; reg < 4; ++reg) {
      int trow = t0w + quad * 4 + reg;
      po[((size_t)bs * 1024 + trow) * 64 + nt * 16 + li] = o[nt][reg];
    }
  if (li == 0) {
#pragma unroll
    for (int reg = 0; reg < 4; ++reg) {
      int trow = t0w + quad * 4 + reg;
      pl[(size_t)bs * 1024 + trow] = ol[reg];
    }
  }
}

// ---------------- combine the two kv-split halves -> attnb (bf16) -----------
__global__ __launch_bounds__(256) void k_combine(
    const float* __restrict__ po, const float* __restrict__ pl,
    unsigned short* __restrict__ attnb) {
  int id = blockIdx.x * 256 + threadIdx.x;
  int dv4 = (id & 15) << 2;
  int t = (id >> 4) & 1023;
  int h = (id >> 14) & 15;
  int b = id >> 18;
  size_t r0 = ((size_t)((b * 2 + 0) * 16 + h)) * 1024 + t;
  size_t r1 = ((size_t)((b * 2 + 1) * 16 + h)) * 1024 + t;
  float inv = 1.0f / (pl[r0] + pl[r1]);
  float4 o0 = *(const float4*)(po + r0 * 64 + dv4);
  float4 o1 = *(const float4*)(po + r1 * 64 + dv4);
  ushort4 res;
  res.x = f2bf((o0.x + o1.x) * inv);
  res.y = f2bf((o0.y + o1.y) * inv);
  res.z = f2bf((o0.z + o1.z) * inv);
  res.w = f2bf((o0.w + o1.w) * inv);
  *(ushort4*)(attnb + ((size_t)(b * 1024 + t)) * 1024 + h * 64 + dv4) = res;
}

extern "C" void kernel_launch(void* const* d_in, const int* in_sizes, int n_in,
                              void* d_out, int out_size, void* d_ws, size_t ws_size,
                              hipStream_t stream) {
  const float* x = (const float*)d_in[0];
  const float* mask = (const float*)d_in[1];
  const float* pos = (const float*)d_in[2];
  const float* mem = (const float*)d_in[3];
  const float* Wq = (const float*)d_in[4];
  const float* Wk = (const float*)d_in[5];
  const float* Wv = (const float*)d_in[6];
  const float* Wr = (const float*)d_in[7];
  const float* rwb = (const float*)d_in[8];
  const float* rrb = (const float*)d_in[9];
  const float* Wo = (const float*)d_in[10];
  float* out = (float*)d_out;

  uint8_t* ws = (uint8_t*)d_ws;
  const size_t MB = 1024 * 1024;
  unsigned short* Vinb = (unsigned short*)(ws + 0);        // 8 MB (dead post-proj)
  unsigned short* WqT = (unsigned short*)(ws + 8 * MB);    // dead post-proj
  unsigned short* WkT = (unsigned short*)(ws + 10 * MB);
  unsigned short* WvT = (unsigned short*)(ws + 12 * MB);
  unsigned short* WrT = (unsigned short*)(ws + 14 * MB);
  unsigned short* WoT = (unsigned short*)(ws + 16 * MB);   // live to end
  unsigned short* Pb = (unsigned short*)(ws + 18 * MB);    // dead post-proj
  unsigned short* qwb = (unsigned short*)(ws + 24 * MB);
  unsigned short* qrb = (unsigned short*)(ws + 28 * MB);
  unsigned short* kb = (unsigned short*)(ws + 32 * MB);
  unsigned short* vtb = (unsigned short*)(ws + 40 * MB);   // [B][H][64][2048]
  unsigned short* rkb = (unsigned short*)(ws + 48 * MB);   // 6 MB
  unsigned short* mbb = (unsigned short*)(ws + 54 * MB);   // 8 MB mask bias bf16
  // overlays (live only after the regions below are dead):
  float* po = (float*)(ws + 0);                            // 16 MB (Vinb..WrT dead)
  float* pl = (float*)(ws + 18 * MB);                      // 256 KB (Pb dead)
  unsigned short* attnb = (unsigned short*)(ws + 19 * MB); // 4 MB (in Pb region)

  hipLaunchKernelGGL(k_prep, dim3(11264), dim3(256), 0, stream,
                     x, mem, pos, mask, Vinb, Pb, mbb);
  hipLaunchKernelGGL(k_wtall, dim3(16, 16, 5), dim3(256), 0, stream,
                     Wq, Wk, Wv, Wr, Wo, WqT, WkT, WvT, WrT, WoT);
  hipLaunchKernelGGL(k_proj, dim3(832), dim3(256), 0, stream,
                     Vinb, Pb, WqT, WkT, WvT, WrT, rwb, rrb, qwb, qrb, kb, vtb, rkb);
  hipLaunchKernelGGL(k_attn, dim3(16, 16, 4), dim3(256), 0, stream,
                     qwb, qrb, kb, vtb, rkb, mbb, po, pl);
  hipLaunchKernelGGL(k_combine, dim3(2048), dim3(256), 0, stream, po, pl, attnb);
  hipLaunchKernelGGL(k_gemm_out64, dim3(32, 8), dim3(256), 0, stream,
                     attnb, WoT, out);
}

// Round 6
// 268.264 us; speedup vs baseline: 1.1884x; 1.0021x over previous
//
#include <hip/hip_runtime.h>
#include <hip/hip_fp16.h>
#include <stdint.h>

#define Bz 2
#define Tq 1024
#define Mm 1024
#define Hh 16
#define Ll 2048
#define Rr 3072

typedef __attribute__((ext_vector_type(8))) short bf16x8;
typedef __attribute__((ext_vector_type(4))) float f32x4;

typedef __attribute__((address_space(3))) uint8_t lds_u8_t;
typedef __attribute__((address_space(1))) uint8_t glb_u8_t;

__device__ __forceinline__ void gl2lds16(const void* g, void* l) {
  __builtin_amdgcn_global_load_lds((const glb_u8_t*)g, (lds_u8_t*)l, 16, 0, 0);
}

__device__ __forceinline__ unsigned short f2bf(float f) {
  unsigned int u = __builtin_bit_cast(unsigned int, f);
  u = u + 0x7fffu + ((u >> 16) & 1u);
  return (unsigned short)(u >> 16);
}
__device__ __forceinline__ float b2f(unsigned short s) {
  unsigned int u = ((unsigned int)s) << 16;
  return __builtin_bit_cast(float, u);
}

// ------- prep: concat+cast values | cast pos | mask -> bf16 additive bias ---
// mask is [B,T,M+T] = 4,194,304 elems -> exactly 4096 blocks (11264 total).
__global__ __launch_bounds__(256) void k_prep(const float* __restrict__ x,
                                              const float* __restrict__ mem,
                                              const float* __restrict__ pos,
                                              const float* __restrict__ mask,
                                              unsigned short* __restrict__ vin,
                                              unsigned short* __restrict__ pb,
                                              unsigned short* __restrict__ mb) {
  int bid = blockIdx.x;
  if (bid < 4096) {
    int idx = bid * 256 + threadIdx.x;
    int e = idx << 2;
    int row = e >> 10, col = e & 1023;
    int b = row >> 11, l = row & 2047;
    const float* s = (l < Mm) ? (mem + (((size_t)b * Mm + l) << 10) + col)
                              : (x + (((size_t)b * Tq + (l - Mm)) << 10) + col);
    float4 v = *(const float4*)s;
    ushort4 o;
    o.x = f2bf(v.x); o.y = f2bf(v.y); o.z = f2bf(v.z); o.w = f2bf(v.w);
    *(ushort4*)(vin + e) = o;
  } else if (bid < 7168) {
    int idx = (bid - 4096) * 256 + threadIdx.x;
    int e = idx << 2;
    float4 v = *(const float4*)(pos + e);
    ushort4 t;
    t.x = f2bf(v.x); t.y = f2bf(v.y); t.z = f2bf(v.z); t.w = f2bf(v.w);
    *(ushort4*)(pb + e) = t;
  } else {
    int idx = (bid - 7168) * 256 + threadIdx.x;
    int e = idx << 2;
    const float BIGM = 1.442695e30f;
    float4 v = *(const float4*)(mask + e);
    ushort4 t;
    t.x = f2bf((1.0f - v.x) * BIGM); t.y = f2bf((1.0f - v.y) * BIGM);
    t.z = f2bf((1.0f - v.z) * BIGM); t.w = f2bf((1.0f - v.w) * BIGM);
    *(ushort4*)(mb + e) = t;
  }
}

// ---------------- prep: transpose-cast 5 weight matrices (1024x1024) --------
__global__ __launch_bounds__(256) void k_wtall(
    const float* __restrict__ w0, const float* __restrict__ w1,
    const float* __restrict__ w2, const float* __restrict__ w3,
    const float* __restrict__ w4,
    unsigned short* __restrict__ t0, unsigned short* __restrict__ t1,
    unsigned short* __restrict__ t2, unsigned short* __restrict__ t3,
    unsigned short* __restrict__ t4) {
  const float* W;
  unsigned short* WT;
  switch (blockIdx.z) {
    case 0: W = w0; WT = t0; break;
    case 1: W = w1; WT = t1; break;
    case 2: W = w2; WT = t2; break;
    case 3: W = w3; WT = t3; break;
    default: W = w4; WT = t4; break;
  }
  __shared__ float tile[64][65];
  int k0 = blockIdx.x * 64, n0 = blockIdx.y * 64;
  int tid = threadIdx.x;
  int rr = tid >> 4, c4 = (tid & 15) * 4;
#pragma unroll
  for (int it = 0; it < 4; ++it) {
    int r = rr + it * 16;
    float4 v = *(const float4*)(W + (size_t)(k0 + r) * 1024 + n0 + c4);
    tile[r][c4] = v.x; tile[r][c4 + 1] = v.y;
    tile[r][c4 + 2] = v.z; tile[r][c4 + 3] = v.w;
  }
  __syncthreads();
#pragma unroll
  for (int it = 0; it < 4; ++it) {
    int n = rr + it * 16;
    ushort4 o;
    o.x = f2bf(tile[c4 + 0][n]); o.y = f2bf(tile[c4 + 1][n]);
    o.z = f2bf(tile[c4 + 2][n]); o.w = f2bf(tile[c4 + 3][n]);
    *(ushort4*)(WT + (size_t)(n0 + n) * 1024 + k0 + c4) = o;
  }
}

// ---------------- bf16 NT GEMM core (m97 structure, K=1024) -----------------
template <int RMAP>
__device__ __forceinline__ void gemm_core(const unsigned short* __restrict__ A,
                                          const unsigned short* __restrict__ Bt,
                                          int m0, int n0, unsigned short* As,
                                          unsigned short* Bs, f32x4 acc[4][4]) {
  const int tid = threadIdx.x;
  const int w = tid >> 6, lane = tid & 63;
  const int quad = lane >> 4, li = lane & 15;
  const int wr = w >> 1, wc = w & 1;
  f32x4 z = {0.f, 0.f, 0.f, 0.f};
#pragma unroll
  for (int mi = 0; mi < 4; ++mi)
#pragma unroll
    for (int ni = 0; ni < 4; ++ni) acc[mi][ni] = z;

  const int rs = lane >> 2;
  const int cs = lane & 3;

  for (int k0 = 0; k0 < 1024; k0 += 32) {
    __syncthreads();
#pragma unroll
    for (int s = 0; s < 2; ++s) {
      int i = w * 2 + s;
      int r = i * 16 + rs;
      int c = cs ^ ((r >> 1) & 3);
      int ar = m0 + r;
      if (RMAP) ar = ar + 1024 + (ar & 1024);
      gl2lds16(A + (size_t)ar * 1024 + k0 + c * 8, (char*)As + i * 1024);
      int br = n0 + r;
      gl2lds16(Bt + (size_t)br * 1024 + k0 + c * 8, (char*)Bs + i * 1024);
    }
    __syncthreads();
    bf16x8 af[4], bfr[4];
#pragma unroll
    for (int mi = 0; mi < 4; ++mi) {
      int r = wr * 64 + mi * 16 + li;
      int ch = quad ^ ((r >> 1) & 3);
      af[mi] = *(const bf16x8*)((const char*)As + r * 64 + ch * 16);
    }
#pragma unroll
    for (int ni = 0; ni < 4; ++ni) {
      int r = wc * 64 + ni * 16 + li;
      int ch = quad ^ ((r >> 1) & 3);
      bfr[ni] = *(const bf16x8*)((const char*)Bs + r * 64 + ch * 16);
    }
#pragma unroll
    for (int mi = 0; mi < 4; ++mi)
#pragma unroll
      for (int ni = 0; ni < 4; ++ni)
        acc[mi][ni] = __builtin_amdgcn_mfma_f32_16x16x32_bf16(
            af[mi], bfr[ni], acc[mi][ni], 0, 0, 0);
  }
}

// fused q (dual-bias) | k | v (direct-transposed out) | rk projections
__global__ __launch_bounds__(256) void k_proj(
    const unsigned short* __restrict__ Vin, const unsigned short* __restrict__ Pb,
    const unsigned short* __restrict__ WqT, const unsigned short* __restrict__ WkT,
    const unsigned short* __restrict__ WvT, const unsigned short* __restrict__ WrT,
    const float* __restrict__ rwb, const float* __restrict__ rrb,
    unsigned short* __restrict__ qwb, unsigned short* __restrict__ qrb,
    unsigned short* __restrict__ kb, unsigned short* __restrict__ vtb,
    unsigned short* __restrict__ rkb) {
  __shared__ unsigned short As[128 * 32];
  __shared__ unsigned short Bs[128 * 32];
  const int t = blockIdx.x;
  const int tid = threadIdx.x, w = tid >> 6, lane = tid & 63;
  const int quad = lane >> 4, li = lane & 15, wr = w >> 1, wc = w & 1;
  f32x4 acc[4][4];

  if (t < 256) {  // k: M=4096, N=1024
    int m0 = (t >> 3) * 128, n0 = (t & 7) * 128;
    gemm_core<0>(Vin, WkT, m0, n0, As, Bs, acc);
#pragma unroll
    for (int mi = 0; mi < 4; ++mi)
#pragma unroll
      for (int ni = 0; ni < 4; ++ni)
#pragma unroll
        for (int reg = 0; reg < 4; ++reg) {
          int rrow = m0 + wr * 64 + mi * 16 + quad * 4 + reg;
          int cc = n0 + wc * 64 + ni * 16 + li;
          kb[(size_t)rrow * 1024 + cc] = f2bf(acc[mi][ni][reg]);
        }
  } else if (t < 512) {  // v: write vtb[b,h,dv,l] directly (ushort4 over l)
    int tt = t - 256;
    int m0 = (tt >> 3) * 128, n0 = (tt & 7) * 128;
    gemm_core<0>(Vin, WvT, m0, n0, As, Bs, acc);
#pragma unroll
    for (int mi = 0; mi < 4; ++mi)
#pragma unroll
      for (int ni = 0; ni < 4; ++ni) {
        int r0 = m0 + wr * 64 + mi * 16 + quad * 4;
        int b = r0 >> 11, l0 = r0 & 2047;
        int cc = n0 + wc * 64 + ni * 16 + li;
        ushort4 o;
        o.x = f2bf(acc[mi][ni][0]); o.y = f2bf(acc[mi][ni][1]);
        o.z = f2bf(acc[mi][ni][2]); o.w = f2bf(acc[mi][ni][3]);
        *(ushort4*)(vtb + ((size_t)(b * 1024 + cc)) * Ll + l0) = o;
      }
  } else if (t < 640) {  // q dual
    int tt = t - 512;
    int m0 = (tt >> 3) * 128, n0 = (tt & 7) * 128;
    gemm_core<1>(Vin, WqT, m0, n0, As, Bs, acc);
#pragma unroll
    for (int mi = 0; mi < 4; ++mi)
#pragma unroll
      for (int ni = 0; ni < 4; ++ni) {
        int cc = n0 + wc * 64 + ni * 16 + li;
        float bw_ = rwb[cc], br_ = rrb[cc];
#pragma unroll
        for (int reg = 0; reg < 4; ++reg) {
          int rrow = m0 + wr * 64 + mi * 16 + quad * 4 + reg;
          size_t off = (size_t)rrow * 1024 + cc;
          qwb[off] = f2bf(acc[mi][ni][reg] + bw_);
          qrb[off] = f2bf(acc[mi][ni][reg] + br_);
        }
      }
  } else {  // rk: M=3072
    int tt = t - 640;
    int m0 = (tt >> 3) * 128, n0 = (tt & 7) * 128;
    gemm_core<0>(Pb, WrT, m0, n0, As, Bs, acc);
#pragma unroll
    for (int mi = 0; mi < 4; ++mi)
#pragma unroll
      for (int ni = 0; ni < 4; ++ni)
#pragma unroll
        for (int reg = 0; reg < 4; ++reg) {
          int rrow = m0 + wr * 64 + mi * 16 + quad * 4 + reg;
          int cc = n0 + wc * 64 + ni * 16 + li;
          rkb[(size_t)rrow * 1024 + cc] = f2bf(acc[mi][ni][reg]);
        }
  }
}

// output projection, 64x128 tile (256 blocks), fp32 out -> d_out
__global__ __launch_bounds__(256) void k_gemm_out64(
    const unsigned short* __restrict__ attnb, const unsigned short* __restrict__ WoT,
    float* __restrict__ out) {
  __shared__ unsigned short As[64 * 32];
  __shared__ unsigned short Bs[128 * 32];
  int m0 = blockIdx.x * 64, n0 = blockIdx.y * 128;
  const int tid = threadIdx.x, w = tid >> 6, lane = tid & 63;
  const int quad = lane >> 4, li = lane & 15, wr = w >> 1, wc = w & 1;
  f32x4 z = {0.f, 0.f, 0.f, 0.f};
  f32x4 acc[2][4];
#pragma unroll
  for (int mi = 0; mi < 2; ++mi)
#pragma unroll
    for (int ni = 0; ni < 4; ++ni) acc[mi][ni] = z;
  const int rs = lane >> 2, cs = lane & 3;
  for (int k0 = 0; k0 < 1024; k0 += 32) {
    __syncthreads();
    {
      int r = w * 16 + rs;
      int c = cs ^ ((r >> 1) & 3);
      gl2lds16(attnb + (size_t)(m0 + r) * 1024 + k0 + c * 8, (char*)As + w * 1024);
    }
#pragma unroll
    for (int s = 0; s < 2; ++s) {
      int i = w * 2 + s;
      int r = i * 16 + rs;
      int c = cs ^ ((r >> 1) & 3);
      gl2lds16(WoT + (size_t)(n0 + r) * 1024 + k0 + c * 8, (char*)Bs + i * 1024);
    }
    __syncthreads();
    bf16x8 af[2], bfr[4];
#pragma unroll
    for (int mi = 0; mi < 2; ++mi) {
      int r = wr * 32 + mi * 16 + li;
      int ch = quad ^ ((r >> 1) & 3);
      af[mi] = *(const bf16x8*)((const char*)As + r * 64 + ch * 16);
    }
#pragma unroll
    for (int ni = 0; ni < 4; ++ni) {
      int r = wc * 64 + ni * 16 + li;
      int ch = quad ^ ((r >> 1) & 3);
      bfr[ni] = *(const bf16x8*)((const char*)Bs + r * 64 + ch * 16);
    }
#pragma unroll
    for (int mi = 0; mi < 2; ++mi)
#pragma unroll
      for (int ni = 0; ni < 4; ++ni)
        acc[mi][ni] = __builtin_amdgcn_mfma_f32_16x16x32_bf16(
            af[mi], bfr[ni], acc[mi][ni], 0, 0, 0);
  }
#pragma unroll
  for (int mi = 0; mi < 2; ++mi)
#pragma unroll
    for (int ni = 0; ni < 4; ++ni)
#pragma unroll
      for (int reg = 0; reg < 4; ++reg) {
        int rrow = m0 + wr * 32 + mi * 16 + quad * 4 + reg;
        int cc = n0 + wc * 64 + ni * 16 + li;
        out[(size_t)rrow * 1024 + cc] = acc[mi][ni][reg];
      }
}

// ---------------- flash attention, single-barrier pipelined K-loop ----------
// grid (T/64, H, B) = 512 blocks, 2/CU. Per jt: ONE __syncthreads (drains the
// prefetch issued a full iteration earlier), then issue jt+1's K/V/R DMAs,
// then compute jt from the other buffer. Ks/Vs double-buffered; Rs = 256-row
// ring (read rows [64jt,+127], write [64jt+128,+63] -- disjoint mod 256).
// LDS = 16K + 16K + 32K + 9216 = 74752 B -> 2 blocks/CU.
__global__ __launch_bounds__(256, 2) void k_attn(
    const unsigned short* __restrict__ qw, const unsigned short* __restrict__ qr,
    const unsigned short* __restrict__ kb, const unsigned short* __restrict__ vt,
    const unsigned short* __restrict__ rkb, const unsigned short* __restrict__ mb,
    unsigned short* __restrict__ attnb) {
  __shared__ unsigned short Ks[2][64 * 64];
  __shared__ unsigned short Vs[2][64 * 64];
  __shared__ unsigned short Rs[256 * 64];
  __shared__ unsigned short Sb[4][16 * 72];  // per-wave s (f16), [row][key]

  const int tid = threadIdx.x;
  const int w = tid >> 6, lane = tid & 63;
  const int quad = lane >> 4, li = lane & 15;
  const int qt = blockIdx.x, h = blockIdx.y, b = blockIdx.z;
  const int t0blk = qt * 64;
  const int t0w = t0blk + w * 16;
  const int rboff = 48 - 16 * w;
  const int rbase0 = Tq - t0blk - 63;

  bf16x8 aqw[2], aqr[2];
  {
    const unsigned short* p1 = qw + ((size_t)((b * Tq + t0w + li) * Hh + h)) * 64;
    aqw[0] = *(const bf16x8*)(p1 + quad * 8);
    aqw[1] = *(const bf16x8*)(p1 + 32 + quad * 8);
    const unsigned short* p2 = qr + ((size_t)((b * Tq + t0w + li) * Hh + h)) * 64;
    aqr[0] = *(const bf16x8*)(p2 + quad * 8);
    aqr[1] = *(const bf16x8*)(p2 + 32 + quad * 8);
  }

  f32x4 z = {0.f, 0.f, 0.f, 0.f};
  f32x4 o[4];
  o[0] = z; o[1] = z; o[2] = z; o[3] = z;
  f32x4 ol = z;

  const int srow = lane >> 3;
  const int scs = lane & 7;
  const float SC = 0.125f * 1.4426950408889634f;
  const short oneb = 0x3F80;
  const bf16x8 onesf = {oneb, oneb, oneb, oneb, oneb, oneb, oneb, oneb};

  unsigned short* pw = &Sb[w][0];
  const unsigned short* mrowA = mb + ((size_t)(b * Tq + t0w + li)) * Ll;
  int srcl[4];
#pragma unroll
  for (int reg = 0; reg < 4; ++reg) {
    int row = quad * 4 + reg;
    srcl[reg] = (lane & 48) + ((li + row + 1) & 15);
  }

  // ---- preload: R ring rows [0,127]; K/V tile jt=0 into buffer 0 ----
#pragma unroll
  for (int s = 0; s < 4; ++s) {
    int i = w * 4 + s;
    int r = i * 8 + srow;
    int gr = rbase0 + r;
    if (gr > Rr - 1) gr = Rr - 1;
    int c = scs ^ (r & 7);
    gl2lds16(rkb + ((size_t)gr * Hh + h) * 64 + c * 8, (char*)Rs + i * 1024);
  }
#pragma unroll
  for (int s = 0; s < 2; ++s) {
    int i = w * 2 + s;
    int r = i * 8 + srow;
    int c = scs ^ (r & 7);
    gl2lds16(kb + ((size_t)((b * Ll + r) * Hh + h)) * 64 + c * 8,
             (char*)Ks[0] + i * 1024);
    gl2lds16(vt + ((size_t)((b * Hh + h) * 64 + r)) * Ll + c * 8,
             (char*)Vs[0] + i * 1024);
  }

  for (int jt = 0; jt < 32; ++jt) {
    const int j0 = jt * 64;
    const int cur = jt & 1, nxt = cur ^ 1;
    __builtin_amdgcn_s_waitcnt(0x0F70);  // vmcnt(0): prefetch complete
    __syncthreads();
    // ---- issue prefetch for jt+1 (drained at the NEXT barrier) ----
    if (jt < 31) {
      const int j0n = j0 + 64;
#pragma unroll
      for (int s = 0; s < 2; ++s) {
        int i = w * 2 + s;
        int r = i * 8 + srow;
        int c = scs ^ (r & 7);
        gl2lds16(kb + ((size_t)((b * Ll + j0n + r) * Hh + h)) * 64 + c * 8,
                 (char*)Ks[nxt] + i * 1024);
        gl2lds16(vt + ((size_t)((b * Hh + h) * 64 + r)) * Ll + j0n + c * 8,
                 (char*)Vs[nxt] + i * 1024);
      }
#pragma unroll
      for (int s = 0; s < 2; ++s) {
        int i2 = w * 2 + s;
        int rr = i2 * 8 + srow;
        int ofs = j0 + 128 + rr;
        int gr = rbase0 + ofs;
        if (gr > Rr - 1) gr = Rr - 1;
        int ring = ofs & 255;
        int c = scs ^ (rr & 7);
        gl2lds16(rkb + ((size_t)gr * Hh + h) * 64 + c * 8, (char*)Rs + ring * 128);
      }
    }
    // ---- compute jt from buffer `cur` ----
    const unsigned short* KsC = Ks[cur];
    const unsigned short* VsC = Vs[cur];
    // content scores (C-layout)
    f32x4 sc[4];
    sc[0] = z; sc[1] = z; sc[2] = z; sc[3] = z;
#pragma unroll
    for (int ks = 0; ks < 2; ++ks)
#pragma unroll
      for (int nt = 0; nt < 4; ++nt) {
        int j = nt * 16 + li;
        int ch = (ks * 4 + quad) ^ (j & 7);
        bf16x8 kf = *(const bf16x8*)((const char*)KsC + j * 128 + ch * 16);
        sc[nt] = __builtin_amdgcn_mfma_f32_16x16x32_bf16(aqw[ks], kf, sc[nt], 0, 0, 0);
      }
    // band scores (ring rows)
    f32x4 bd[5];
    bd[0] = z; bd[1] = z; bd[2] = z; bd[3] = z; bd[4] = z;
#pragma unroll
    for (int ks = 0; ks < 2; ++ks)
#pragma unroll
      for (int nt = 0; nt < 5; ++nt) {
        int pr = (rboff + nt * 16 + li + j0) & 255;
        int ch = (ks * 4 + quad) ^ (pr & 7);
        bf16x8 rf = *(const bf16x8*)((const char*)Rs + pr * 128 + ch * 16);
        bd[nt] = __builtin_amdgcn_mfma_f32_16x16x32_bf16(aqr[ks], rf, bd[nt], 0, 0, 0);
      }
    // rotate sc into band column space
    float rot[4][4];
#pragma unroll
    for (int nt = 0; nt < 4; ++nt)
#pragma unroll
      for (int reg = 0; reg < 4; ++reg)
        rot[nt][reg] = __shfl(sc[nt][reg], srcl[reg], 64);
    // s = sc(aligned) + bd, store f16 at shifted slot (row, jj)
#pragma unroll
    for (int nt = 0; nt < 5; ++nt)
#pragma unroll
      for (int reg = 0; reg < 4; ++reg) {
        int row = quad * 4 + reg;
        int jj = nt * 16 + li + row - 15;
        int ntlo = (nt == 0) ? 3 : (nt - 1);
        int nthi = (nt > 3) ? 0 : nt;
        float val = ((li + row) >= 15) ? rot[nthi][reg] : rot[ntlo][reg];
        float s = val + bd[nt][reg];
        if ((unsigned)jj < 64u)
          pw[row * 72 + jj] = __builtin_bit_cast(unsigned short, __float2half(s));
      }
    __builtin_amdgcn_s_waitcnt(0xc07f);  // lgkmcnt(0) only
    // A-layout: s reads + mask b128 + exp2 -> PV MFMA from registers
#pragma unroll
    for (int ks = 0; ks < 2; ++ks) {
      const int cofs = ks * 32 + quad * 8;
      ushort4 s0 = *(const ushort4*)(pw + li * 72 + cofs);
      ushort4 s1 = *(const ushort4*)(pw + li * 72 + cofs + 4);
      bf16x8 mv = *(const bf16x8*)(mrowA + j0 + cofs);
      unsigned short su[8] = {s0.x, s0.y, s0.z, s0.w, s1.x, s1.y, s1.z, s1.w};
      bf16x8 ap;
#pragma unroll
      for (int i2 = 0; i2 < 8; ++i2) {
        float sf = __half2float(__builtin_bit_cast(__half, su[i2]));
        float mvf = b2f((unsigned short)mv[i2]);
        float p = exp2f(sf * SC - mvf);
        ap[i2] = (short)f2bf(p);
      }
      ol = __builtin_amdgcn_mfma_f32_16x16x32_bf16(ap, onesf, ol, 0, 0, 0);
#pragma unroll
      for (int nt = 0; nt < 4; ++nt) {
        int dv = nt * 16 + li;
        int ch = (ks * 4 + quad) ^ (dv & 7);
        bf16x8 vf = *(const bf16x8*)((const char*)VsC + dv * 128 + ch * 16);
        o[nt] = __builtin_amdgcn_mfma_f32_16x16x32_bf16(ap, vf, o[nt], 0, 0, 0);
      }
    }
  }
  // epilogue: normalized bf16 output [b, t, h*64+dv]
  float inv[4];
#pragma unroll
  for (int reg = 0; reg < 4; ++reg) inv[reg] = 1.0f / ol[reg];
#pragma unroll
  for (int nt = 0; nt < 4; ++nt)
#pragma unroll
    for (int reg = 0; reg < 4; ++reg) {
      int trow = t0w + quad * 4 + reg;
      attnb[((size_t)(b * Tq + trow)) * 1024 + h * 64 + nt * 16 + li] =
          f2bf(o[nt][reg] * inv[reg]);
    }
}

extern "C" void kernel_launch(void* const* d_in, const int* in_sizes, int n_in,
                              void* d_out, int out_size, void* d_ws, size_t ws_size,
                              hipStream_t stream) {
  const float* x = (const float*)d_in[0];
  const float* mask = (const float*)d_in[1];
  const float* pos = (const float*)d_in[2];
  const float* mem = (const float*)d_in[3];
  const float* Wq = (const float*)d_in[4];
  const float* Wk = (const float*)d_in[5];
  const float* Wv = (const float*)d_in[6];
  const float* Wr = (const float*)d_in[7];
  const float* rwb = (const float*)d_in[8];
  const float* rrb = (const float*)d_in[9];
  const float* Wo = (const float*)d_in[10];
  float* out = (float*)d_out;

  uint8_t* ws = (uint8_t*)d_ws;
  const size_t MB = 1024 * 1024;
  unsigned short* Vinb = (unsigned short*)(ws + 0);        // 8 MB (dead post-proj)
  unsigned short* WqT = (unsigned short*)(ws + 8 * MB);
  unsigned short* WkT = (unsigned short*)(ws + 10 * MB);
  unsigned short* WvT = (unsigned short*)(ws + 12 * MB);
  unsigned short* WrT = (unsigned short*)(ws + 14 * MB);
  unsigned short* WoT = (unsigned short*)(ws + 16 * MB);   // live to end
  unsigned short* Pb = (unsigned short*)(ws + 18 * MB);    // dead post-proj
  unsigned short* qwb = (unsigned short*)(ws + 24 * MB);
  unsigned short* qrb = (unsigned short*)(ws + 28 * MB);
  unsigned short* kb = (unsigned short*)(ws + 32 * MB);
  unsigned short* vtb = (unsigned short*)(ws + 40 * MB);   // [B][H][64][2048]
  unsigned short* rkb = (unsigned short*)(ws + 48 * MB);   // 6 MB
  unsigned short* mbb = (unsigned short*)(ws + 54 * MB);   // 8 MB mask bias bf16
  unsigned short* attnb = (unsigned short*)(ws + 19 * MB); // 4 MB (in Pb region)

  hipLaunchKernelGGL(k_prep, dim3(11264), dim3(256), 0, stream,
                     x, mem, pos, mask, Vinb, Pb, mbb);
  hipLaunchKernelGGL(k_wtall, dim3(16, 16, 5), dim3(256), 0, stream,
                     Wq, Wk, Wv, Wr, Wo, WqT, WkT, WvT, WrT, WoT);
  hipLaunchKernelGGL(k_proj, dim3(832), dim3(256), 0, stream,
                     Vinb, Pb, WqT, WkT, WvT, WrT, rwb, rrb, qwb, qrb, kb, vtb, rkb);
  hipLaunchKernelGGL(k_attn, dim3(16, 16, 2), dim3(256), 0, stream,
                     qwb, qrb, kb, vtb, rkb, mbb, attnb);
  hipLaunchKernelGGL(k_gemm_out64, dim3(32, 8), dim3(256), 0, stream,
                     attnb, WoT, out);
}

// Round 7
// 265.558 us; speedup vs baseline: 1.2005x; 1.0102x over previous
//
#include <hip/hip_runtime.h>
#include <hip/hip_fp16.h>
#include <stdint.h>

#define Bz 2
#define Tq 1024
#define Mm 1024
#define Hh 16
#define Ll 2048
#define Rr 3072

typedef __attribute__((ext_vector_type(8))) short bf16x8;
typedef __attribute__((ext_vector_type(4))) float f32x4;

typedef __attribute__((address_space(3))) uint8_t lds_u8_t;
typedef __attribute__((address_space(1))) uint8_t glb_u8_t;

__device__ __forceinline__ void gl2lds16(const void* g, void* l) {
  __builtin_amdgcn_global_load_lds((const glb_u8_t*)g, (lds_u8_t*)l, 16, 0, 0);
}

__device__ __forceinline__ unsigned short f2bf(float f) {
  unsigned int u = __builtin_bit_cast(unsigned int, f);
  u = u + 0x7fffu + ((u >> 16) & 1u);
  return (unsigned short)(u >> 16);
}
__device__ __forceinline__ float b2f(unsigned short s) {
  unsigned int u = ((unsigned int)s) << 16;
  return __builtin_bit_cast(float, u);
}

// ------- prep: concat+cast values | cast pos | mask -> bf16 additive bias ---
// mask is [B,T,M+T] = 4,194,304 elems -> exactly 4096 blocks (11264 total).
__global__ __launch_bounds__(256) void k_prep(const float* __restrict__ x,
                                              const float* __restrict__ mem,
                                              const float* __restrict__ pos,
                                              const float* __restrict__ mask,
                                              unsigned short* __restrict__ vin,
                                              unsigned short* __restrict__ pb,
                                              unsigned short* __restrict__ mb) {
  int bid = blockIdx.x;
  if (bid < 4096) {
    int idx = bid * 256 + threadIdx.x;
    int e = idx << 2;
    int row = e >> 10, col = e & 1023;
    int b = row >> 11, l = row & 2047;
    const float* s = (l < Mm) ? (mem + (((size_t)b * Mm + l) << 10) + col)
                              : (x + (((size_t)b * Tq + (l - Mm)) << 10) + col);
    float4 v = *(const float4*)s;
    ushort4 o;
    o.x = f2bf(v.x); o.y = f2bf(v.y); o.z = f2bf(v.z); o.w = f2bf(v.w);
    *(ushort4*)(vin + e) = o;
  } else if (bid < 7168) {
    int idx = (bid - 4096) * 256 + threadIdx.x;
    int e = idx << 2;
    float4 v = *(const float4*)(pos + e);
    ushort4 t;
    t.x = f2bf(v.x); t.y = f2bf(v.y); t.z = f2bf(v.z); t.w = f2bf(v.w);
    *(ushort4*)(pb + e) = t;
  } else {
    int idx = (bid - 7168) * 256 + threadIdx.x;
    int e = idx << 2;
    const float BIGM = 1.442695e30f;
    float4 v = *(const float4*)(mask + e);
    ushort4 t;
    t.x = f2bf((1.0f - v.x) * BIGM); t.y = f2bf((1.0f - v.y) * BIGM);
    t.z = f2bf((1.0f - v.z) * BIGM); t.w = f2bf((1.0f - v.w) * BIGM);
    *(ushort4*)(mb + e) = t;
  }
}

// ---------------- prep: transpose-cast 5 weight matrices (1024x1024) --------
__global__ __launch_bounds__(256) void k_wtall(
    const float* __restrict__ w0, const float* __restrict__ w1,
    const float* __restrict__ w2, const float* __restrict__ w3,
    const float* __restrict__ w4,
    unsigned short* __restrict__ t0, unsigned short* __restrict__ t1,
    unsigned short* __restrict__ t2, unsigned short* __restrict__ t3,
    unsigned short* __restrict__ t4) {
  const float* W;
  unsigned short* WT;
  switch (blockIdx.z) {
    case 0: W = w0; WT = t0; break;
    case 1: W = w1; WT = t1; break;
    case 2: W = w2; WT = t2; break;
    case 3: W = w3; WT = t3; break;
    default: W = w4; WT = t4; break;
  }
  __shared__ float tile[64][65];
  int k0 = blockIdx.x * 64, n0 = blockIdx.y * 64;
  int tid = threadIdx.x;
  int rr = tid >> 4, c4 = (tid & 15) * 4;
#pragma unroll
  for (int it = 0; it < 4; ++it) {
    int r = rr + it * 16;
    float4 v = *(const float4*)(W + (size_t)(k0 + r) * 1024 + n0 + c4);
    tile[r][c4] = v.x; tile[r][c4 + 1] = v.y;
    tile[r][c4 + 2] = v.z; tile[r][c4 + 3] = v.w;
  }
  __syncthreads();
#pragma unroll
  for (int it = 0; it < 4; ++it) {
    int n = rr + it * 16;
    ushort4 o;
    o.x = f2bf(tile[c4 + 0][n]); o.y = f2bf(tile[c4 + 1][n]);
    o.z = f2bf(tile[c4 + 2][n]); o.w = f2bf(tile[c4 + 3][n]);
    *(ushort4*)(WT + (size_t)(n0 + n) * 1024 + k0 + c4) = o;
  }
}

// ---------------- bf16 NT GEMM core (m97 structure, K=1024) -----------------
template <int RMAP>
__device__ __forceinline__ void gemm_core(const unsigned short* __restrict__ A,
                                          const unsigned short* __restrict__ Bt,
                                          int m0, int n0, unsigned short* As,
                                          unsigned short* Bs, f32x4 acc[4][4]) {
  const int tid = threadIdx.x;
  const int w = tid >> 6, lane = tid & 63;
  const int quad = lane >> 4, li = lane & 15;
  const int wr = w >> 1, wc = w & 1;
  f32x4 z = {0.f, 0.f, 0.f, 0.f};
#pragma unroll
  for (int mi = 0; mi < 4; ++mi)
#pragma unroll
    for (int ni = 0; ni < 4; ++ni) acc[mi][ni] = z;

  const int rs = lane >> 2;
  const int cs = lane & 3;

  for (int k0 = 0; k0 < 1024; k0 += 32) {
    __syncthreads();
#pragma unroll
    for (int s = 0; s < 2; ++s) {
      int i = w * 2 + s;
      int r = i * 16 + rs;
      int c = cs ^ ((r >> 1) & 3);
      int ar = m0 + r;
      if (RMAP) ar = ar + 1024 + (ar & 1024);
      gl2lds16(A + (size_t)ar * 1024 + k0 + c * 8, (char*)As + i * 1024);
      int br = n0 + r;
      gl2lds16(Bt + (size_t)br * 1024 + k0 + c * 8, (char*)Bs + i * 1024);
    }
    __syncthreads();
    bf16x8 af[4], bfr[4];
#pragma unroll
    for (int mi = 0; mi < 4; ++mi) {
      int r = wr * 64 + mi * 16 + li;
      int ch = quad ^ ((r >> 1) & 3);
      af[mi] = *(const bf16x8*)((const char*)As + r * 64 + ch * 16);
    }
#pragma unroll
    for (int ni = 0; ni < 4; ++ni) {
      int r = wc * 64 + ni * 16 + li;
      int ch = quad ^ ((r >> 1) & 3);
      bfr[ni] = *(const bf16x8*)((const char*)Bs + r * 64 + ch * 16);
    }
#pragma unroll
    for (int mi = 0; mi < 4; ++mi)
#pragma unroll
      for (int ni = 0; ni < 4; ++ni)
        acc[mi][ni] = __builtin_amdgcn_mfma_f32_16x16x32_bf16(
            af[mi], bfr[ni], acc[mi][ni], 0, 0, 0);
  }
}

// fused q (dual-bias) | k | v (direct-transposed out) | rk projections
__global__ __launch_bounds__(256) void k_proj(
    const unsigned short* __restrict__ Vin, const unsigned short* __restrict__ Pb,
    const unsigned short* __restrict__ WqT, const unsigned short* __restrict__ WkT,
    const unsigned short* __restrict__ WvT, const unsigned short* __restrict__ WrT,
    const float* __restrict__ rwb, const float* __restrict__ rrb,
    unsigned short* __restrict__ qwb, unsigned short* __restrict__ qrb,
    unsigned short* __restrict__ kb, unsigned short* __restrict__ vtb,
    unsigned short* __restrict__ rkb) {
  __shared__ unsigned short As[128 * 32];
  __shared__ unsigned short Bs[128 * 32];
  const int t = blockIdx.x;
  const int tid = threadIdx.x, w = tid >> 6, lane = tid & 63;
  const int quad = lane >> 4, li = lane & 15, wr = w >> 1, wc = w & 1;
  f32x4 acc[4][4];

  if (t < 256) {  // k: M=4096, N=1024
    int m0 = (t >> 3) * 128, n0 = (t & 7) * 128;
    gemm_core<0>(Vin, WkT, m0, n0, As, Bs, acc);
#pragma unroll
    for (int mi = 0; mi < 4; ++mi)
#pragma unroll
      for (int ni = 0; ni < 4; ++ni)
#pragma unroll
        for (int reg = 0; reg < 4; ++reg) {
          int rrow = m0 + wr * 64 + mi * 16 + quad * 4 + reg;
          int cc = n0 + wc * 64 + ni * 16 + li;
          kb[(size_t)rrow * 1024 + cc] = f2bf(acc[mi][ni][reg]);
        }
  } else if (t < 512) {  // v: write vtb[b,h,dv,l] directly (ushort4 over l)
    int tt = t - 256;
    int m0 = (tt >> 3) * 128, n0 = (tt & 7) * 128;
    gemm_core<0>(Vin, WvT, m0, n0, As, Bs, acc);
#pragma unroll
    for (int mi = 0; mi < 4; ++mi)
#pragma unroll
      for (int ni = 0; ni < 4; ++ni) {
        int r0 = m0 + wr * 64 + mi * 16 + quad * 4;
        int b = r0 >> 11, l0 = r0 & 2047;
        int cc = n0 + wc * 64 + ni * 16 + li;
        ushort4 o;
        o.x = f2bf(acc[mi][ni][0]); o.y = f2bf(acc[mi][ni][1]);
        o.z = f2bf(acc[mi][ni][2]); o.w = f2bf(acc[mi][ni][3]);
        *(ushort4*)(vtb + ((size_t)(b * 1024 + cc)) * Ll + l0) = o;
      }
  } else if (t < 640) {  // q dual
    int tt = t - 512;
    int m0 = (tt >> 3) * 128, n0 = (tt & 7) * 128;
    gemm_core<1>(Vin, WqT, m0, n0, As, Bs, acc);
#pragma unroll
    for (int mi = 0; mi < 4; ++mi)
#pragma unroll
      for (int ni = 0; ni < 4; ++ni) {
        int cc = n0 + wc * 64 + ni * 16 + li;
        float bw_ = rwb[cc], br_ = rrb[cc];
#pragma unroll
        for (int reg = 0; reg < 4; ++reg) {
          int rrow = m0 + wr * 64 + mi * 16 + quad * 4 + reg;
          size_t off = (size_t)rrow * 1024 + cc;
          qwb[off] = f2bf(acc[mi][ni][reg] + bw_);
          qrb[off] = f2bf(acc[mi][ni][reg] + br_);
        }
      }
  } else {  // rk: M=3072
    int tt = t - 640;
    int m0 = (tt >> 3) * 128, n0 = (tt & 7) * 128;
    gemm_core<0>(Pb, WrT, m0, n0, As, Bs, acc);
#pragma unroll
    for (int mi = 0; mi < 4; ++mi)
#pragma unroll
      for (int ni = 0; ni < 4; ++ni)
#pragma unroll
        for (int reg = 0; reg < 4; ++reg) {
          int rrow = m0 + wr * 64 + mi * 16 + quad * 4 + reg;
          int cc = n0 + wc * 64 + ni * 16 + li;
          rkb[(size_t)rrow * 1024 + cc] = f2bf(acc[mi][ni][reg]);
        }
  }
}

// output projection, 64x128 tile (256 blocks), fp32 out -> d_out
__global__ __launch_bounds__(256) void k_gemm_out64(
    const unsigned short* __restrict__ attnb, const unsigned short* __restrict__ WoT,
    float* __restrict__ out) {
  __shared__ unsigned short As[64 * 32];
  __shared__ unsigned short Bs[128 * 32];
  int m0 = blockIdx.x * 64, n0 = blockIdx.y * 128;
  const int tid = threadIdx.x, w = tid >> 6, lane = tid & 63;
  const int quad = lane >> 4, li = lane & 15, wr = w >> 1, wc = w & 1;
  f32x4 z = {0.f, 0.f, 0.f, 0.f};
  f32x4 acc[2][4];
#pragma unroll
  for (int mi = 0; mi < 2; ++mi)
#pragma unroll
    for (int ni = 0; ni < 4; ++ni) acc[mi][ni] = z;
  const int rs = lane >> 2, cs = lane & 3;
  for (int k0 = 0; k0 < 1024; k0 += 32) {
    __syncthreads();
    {
      int r = w * 16 + rs;
      int c = cs ^ ((r >> 1) & 3);
      gl2lds16(attnb + (size_t)(m0 + r) * 1024 + k0 + c * 8, (char*)As + w * 1024);
    }
#pragma unroll
    for (int s = 0; s < 2; ++s) {
      int i = w * 2 + s;
      int r = i * 16 + rs;
      int c = cs ^ ((r >> 1) & 3);
      gl2lds16(WoT + (size_t)(n0 + r) * 1024 + k0 + c * 8, (char*)Bs + i * 1024);
    }
    __syncthreads();
    bf16x8 af[2], bfr[4];
#pragma unroll
    for (int mi = 0; mi < 2; ++mi) {
      int r = wr * 32 + mi * 16 + li;
      int ch = quad ^ ((r >> 1) & 3);
      af[mi] = *(const bf16x8*)((const char*)As + r * 64 + ch * 16);
    }
#pragma unroll
    for (int ni = 0; ni < 4; ++ni) {
      int r = wc * 64 + ni * 16 + li;
      int ch = quad ^ ((r >> 1) & 3);
      bfr[ni] = *(const bf16x8*)((const char*)Bs + r * 64 + ch * 16);
    }
#pragma unroll
    for (int mi = 0; mi < 2; ++mi)
#pragma unroll
      for (int ni = 0; ni < 4; ++ni)
        acc[mi][ni] = __builtin_amdgcn_mfma_f32_16x16x32_bf16(
            af[mi], bfr[ni], acc[mi][ni], 0, 0, 0);
  }
#pragma unroll
  for (int mi = 0; mi < 2; ++mi)
#pragma unroll
    for (int ni = 0; ni < 4; ++ni)
#pragma unroll
      for (int reg = 0; reg < 4; ++reg) {
        int rrow = m0 + wr * 32 + mi * 16 + quad * 4 + reg;
        int cc = n0 + wc * 64 + ni * 16 + li;
        out[(size_t)rrow * 1024 + cc] = acc[mi][ni][reg];
      }
}

// ---------------- flash attention, single-barrier pipelined K-loop ----------
// Per jt: vmcnt(0)+barrier (drains prefetch issued a full iteration ago),
// then THIS jt's mask loads (oldest in vm queue -> their use waits vmcnt(6),
// NOT 0 -- prefetches stay in flight), then jt+1 prefetch DMAs, then compute.
// Ks/Vs double-buffered; Rs = 256-row ring. LDS 74752 B -> 2 blocks/CU.
__global__ __launch_bounds__(256, 2) void k_attn(
    const unsigned short* __restrict__ qw, const unsigned short* __restrict__ qr,
    const unsigned short* __restrict__ kb, const unsigned short* __restrict__ vt,
    const unsigned short* __restrict__ rkb, const unsigned short* __restrict__ mb,
    unsigned short* __restrict__ attnb) {
  __shared__ unsigned short Ks[2][64 * 64];
  __shared__ unsigned short Vs[2][64 * 64];
  __shared__ unsigned short Rs[256 * 64];
  __shared__ unsigned short Sb[4][16 * 72];  // per-wave s (f16), [row][key]

  const int tid = threadIdx.x;
  const int w = tid >> 6, lane = tid & 63;
  const int quad = lane >> 4, li = lane & 15;
  const int qt = blockIdx.x, h = blockIdx.y, b = blockIdx.z;
  const int t0blk = qt * 64;
  const int t0w = t0blk + w * 16;
  const int rboff = 48 - 16 * w;
  const int rbase0 = Tq - t0blk - 63;

  bf16x8 aqw[2], aqr[2];
  {
    const unsigned short* p1 = qw + ((size_t)((b * Tq + t0w + li) * Hh + h)) * 64;
    aqw[0] = *(const bf16x8*)(p1 + quad * 8);
    aqw[1] = *(const bf16x8*)(p1 + 32 + quad * 8);
    const unsigned short* p2 = qr + ((size_t)((b * Tq + t0w + li) * Hh + h)) * 64;
    aqr[0] = *(const bf16x8*)(p2 + quad * 8);
    aqr[1] = *(const bf16x8*)(p2 + 32 + quad * 8);
  }

  f32x4 z = {0.f, 0.f, 0.f, 0.f};
  f32x4 o[4];
  o[0] = z; o[1] = z; o[2] = z; o[3] = z;
  f32x4 ol = z;

  const int srow = lane >> 3;
  const int scs = lane & 7;
  const float SC = 0.125f * 1.4426950408889634f;
  const short oneb = 0x3F80;
  const bf16x8 onesf = {oneb, oneb, oneb, oneb, oneb, oneb, oneb, oneb};

  unsigned short* pw = &Sb[w][0];
  const unsigned short* mrowA = mb + ((size_t)(b * Tq + t0w + li)) * Ll;
  int srcl[4];
#pragma unroll
  for (int reg = 0; reg < 4; ++reg) {
    int row = quad * 4 + reg;
    srcl[reg] = (lane & 48) + ((li + row + 1) & 15);
  }

  // ---- preload: R ring rows [0,127]; K/V tile jt=0 into buffer 0 ----
#pragma unroll
  for (int s = 0; s < 4; ++s) {
    int i = w * 4 + s;
    int r = i * 8 + srow;
    int gr = rbase0 + r;
    if (gr > Rr - 1) gr = Rr - 1;
    int c = scs ^ (r & 7);
    gl2lds16(rkb + ((size_t)gr * Hh + h) * 64 + c * 8, (char*)Rs + i * 1024);
  }
#pragma unroll
  for (int s = 0; s < 2; ++s) {
    int i = w * 2 + s;
    int r = i * 8 + srow;
    int c = scs ^ (r & 7);
    gl2lds16(kb + ((size_t)((b * Ll + r) * Hh + h)) * 64 + c * 8,
             (char*)Ks[0] + i * 1024);
    gl2lds16(vt + ((size_t)((b * Hh + h) * 64 + r)) * Ll + c * 8,
             (char*)Vs[0] + i * 1024);
  }

  for (int jt = 0; jt < 32; ++jt) {
    const int j0 = jt * 64;
    const int cur = jt & 1, nxt = cur ^ 1;
    __builtin_amdgcn_s_waitcnt(0x0F70);  // vmcnt(0): prefetch complete
    __syncthreads();
    // ---- THIS jt's mask loads FIRST (oldest in vm queue) ----
    bf16x8 mv0 = *(const bf16x8*)(mrowA + j0 + quad * 8);
    bf16x8 mv1 = *(const bf16x8*)(mrowA + j0 + 32 + quad * 8);
    asm volatile("" ::: "memory");  // pin: mask issue precedes prefetch DMAs
    // ---- issue prefetch for jt+1 (drained at the NEXT barrier) ----
    if (jt < 31) {
      const int j0n = j0 + 64;
#pragma unroll
      for (int s = 0; s < 2; ++s) {
        int i = w * 2 + s;
        int r = i * 8 + srow;
        int c = scs ^ (r & 7);
        gl2lds16(kb + ((size_t)((b * Ll + j0n + r) * Hh + h)) * 64 + c * 8,
                 (char*)Ks[nxt] + i * 1024);
        gl2lds16(vt + ((size_t)((b * Hh + h) * 64 + r)) * Ll + j0n + c * 8,
                 (char*)Vs[nxt] + i * 1024);
      }
#pragma unroll
      for (int s = 0; s < 2; ++s) {
        int i2 = w * 2 + s;
        int rr = i2 * 8 + srow;
        int ofs = j0 + 128 + rr;
        int gr = rbase0 + ofs;
        if (gr > Rr - 1) gr = Rr - 1;
        int ring = ofs & 255;
        int c = scs ^ (rr & 7);
        gl2lds16(rkb + ((size_t)gr * Hh + h) * 64 + c * 8, (char*)Rs + ring * 128);
      }
    }
    // ---- compute jt from buffer `cur` ----
    const unsigned short* KsC = Ks[cur];
    const unsigned short* VsC = Vs[cur];
    // content scores (C-layout)
    f32x4 sc[4];
    sc[0] = z; sc[1] = z; sc[2] = z; sc[3] = z;
#pragma unroll
    for (int ks = 0; ks < 2; ++ks)
#pragma unroll
      for (int nt = 0; nt < 4; ++nt) {
        int j = nt * 16 + li;
        int ch = (ks * 4 + quad) ^ (j & 7);
        bf16x8 kf = *(const bf16x8*)((const char*)KsC + j * 128 + ch * 16);
        sc[nt] = __builtin_amdgcn_mfma_f32_16x16x32_bf16(aqw[ks], kf, sc[nt], 0, 0, 0);
      }
    // band scores (ring rows)
    f32x4 bd[5];
    bd[0] = z; bd[1] = z; bd[2] = z; bd[3] = z; bd[4] = z;
#pragma unroll
    for (int ks = 0; ks < 2; ++ks)
#pragma unroll
      for (int nt = 0; nt < 5; ++nt) {
        int pr = (rboff + nt * 16 + li + j0) & 255;
        int ch = (ks * 4 + quad) ^ (pr & 7);
        bf16x8 rf = *(const bf16x8*)((const char*)Rs + pr * 128 + ch * 16);
        bd[nt] = __builtin_amdgcn_mfma_f32_16x16x32_bf16(aqr[ks], rf, bd[nt], 0, 0, 0);
      }
    // rotate sc into band column space
    float rot[4][4];
#pragma unroll
    for (int nt = 0; nt < 4; ++nt)
#pragma unroll
      for (int reg = 0; reg < 4; ++reg)
        rot[nt][reg] = __shfl(sc[nt][reg], srcl[reg], 64);
    // s = sc(aligned) + bd, store f16 at shifted slot (row, jj)
#pragma unroll
    for (int nt = 0; nt < 5; ++nt)
#pragma unroll
      for (int reg = 0; reg < 4; ++reg) {
        int row = quad * 4 + reg;
        int jj = nt * 16 + li + row - 15;
        int ntlo = (nt == 0) ? 3 : (nt - 1);
        int nthi = (nt > 3) ? 0 : nt;
        float val = ((li + row) >= 15) ? rot[nthi][reg] : rot[ntlo][reg];
        float s = val + bd[nt][reg];
        if ((unsigned)jj < 64u)
          pw[row * 72 + jj] = __builtin_bit_cast(unsigned short, __float2half(s));
      }
    __builtin_amdgcn_s_waitcnt(0xc07f);  // lgkmcnt(0) only
    // A-layout: s reads + pre-issued mask + exp2 -> PV MFMA from registers
#pragma unroll
    for (int ks = 0; ks < 2; ++ks) {
      const int cofs = ks * 32 + quad * 8;
      ushort4 s0 = *(const ushort4*)(pw + li * 72 + cofs);
      ushort4 s1 = *(const ushort4*)(pw + li * 72 + cofs + 4);
      bf16x8 mv = ks ? mv1 : mv0;
      unsigned short su[8] = {s0.x, s0.y, s0.z, s0.w, s1.x, s1.y, s1.z, s1.w};
      bf16x8 ap;
#pragma unroll
      for (int i2 = 0; i2 < 8; ++i2) {
        float sf = __half2float(__builtin_bit_cast(__half, su[i2]));
        float mvf = b2f((unsigned short)mv[i2]);
        float p = exp2f(sf * SC - mvf);
        ap[i2] = (short)f2bf(p);
      }
      ol = __builtin_amdgcn_mfma_f32_16x16x32_bf16(ap, onesf, ol, 0, 0, 0);
#pragma unroll
      for (int nt = 0; nt < 4; ++nt) {
        int dv = nt * 16 + li;
        int ch = (ks * 4 + quad) ^ (dv & 7);
        bf16x8 vf = *(const bf16x8*)((const char*)VsC + dv * 128 + ch * 16);
        o[nt] = __builtin_amdgcn_mfma_f32_16x16x32_bf16(ap, vf, o[nt], 0, 0, 0);
      }
    }
  }
  // epilogue: normalized bf16 output [b, t, h*64+dv]
  float inv[4];
#pragma unroll
  for (int reg = 0; reg < 4; ++reg) inv[reg] = 1.0f / ol[reg];
#pragma unroll
  for (int nt = 0; nt < 4; ++nt)
#pragma unroll
    for (int reg = 0; reg < 4; ++reg) {
      int trow = t0w + quad * 4 + reg;
      attnb[((size_t)(b * Tq + trow)) * 1024 + h * 64 + nt * 16 + li] =
          f2bf(o[nt][reg] * inv[reg]);
    }
}

extern "C" void kernel_launch(void* const* d_in, const int* in_sizes, int n_in,
                              void* d_out, int out_size, void* d_ws, size_t ws_size,
                              hipStream_t stream) {
  const float* x = (const float*)d_in[0];
  const float* mask = (const float*)d_in[1];
  const float* pos = (const float*)d_in[2];
  const float* mem = (const float*)d_in[3];
  const float* Wq = (const float*)d_in[4];
  const float* Wk = (const float*)d_in[5];
  const float* Wv = (const float*)d_in[6];
  const float* Wr = (const float*)d_in[7];
  const float* rwb = (const float*)d_in[8];
  const float* rrb = (const float*)d_in[9];
  const float* Wo = (const float*)d_in[10];
  float* out = (float*)d_out;

  uint8_t* ws = (uint8_t*)d_ws;
  const size_t MB = 1024 * 1024;
  unsigned short* Vinb = (unsigned short*)(ws + 0);        // 8 MB (dead post-proj)
  unsigned short* WqT = (unsigned short*)(ws + 8 * MB);
  unsigned short* WkT = (unsigned short*)(ws + 10 * MB);
  unsigned short* WvT = (unsigned short*)(ws + 12 * MB);
  unsigned short* WrT = (unsigned short*)(ws + 14 * MB);
  unsigned short* WoT = (unsigned short*)(ws + 16 * MB);   // live to end
  unsigned short* Pb = (unsigned short*)(ws + 18 * MB);    // dead post-proj
  unsigned short* qwb = (unsigned short*)(ws + 24 * MB);
  unsigned short* qrb = (unsigned short*)(ws + 28 * MB);
  unsigned short* kb = (unsigned short*)(ws + 32 * MB);
  unsigned short* vtb = (unsigned short*)(ws + 40 * MB);   // [B][H][64][2048]
  unsigned short* rkb = (unsigned short*)(ws + 48 * MB);   // 6 MB
  unsigned short* mbb = (unsigned short*)(ws + 54 * MB);   // 8 MB mask bias bf16
  unsigned short* attnb = (unsigned short*)(ws + 19 * MB); // 4 MB (in Pb region)

  hipLaunchKernelGGL(k_prep, dim3(11264), dim3(256), 0, stream,
                     x, mem, pos, mask, Vinb, Pb, mbb);
  hipLaunchKernelGGL(k_wtall, dim3(16, 16, 5), dim3(256), 0, stream,
                     Wq, Wk, Wv, Wr, Wo, WqT, WkT, WvT, WrT, WoT);
  hipLaunchKernelGGL(k_proj, dim3(832), dim3(256), 0, stream,
                     Vinb, Pb, WqT, WkT, WvT, WrT, rwb, rrb, qwb, qrb, kb, vtb, rkb);
  hipLaunchKernelGGL(k_attn, dim3(16, 16, 2), dim3(256), 0, stream,
                     qwb, qrb, kb, vtb, rkb, mbb, attnb);
  hipLaunchKernelGGL(k_gemm_out64, dim3(32, 8), dim3(256), 0, stream,
                     attnb, WoT, out);
}